// Round 1
// baseline (1771.502 us; speedup 1.0000x reference)
//
#include <hip/hip_runtime.h>
#include <math.h>

#define HW     16384
#define WIDTH  128
#define CDIM   384
#define QKVC   1152
#define HEADS  8
#define CH     48
#define NSPLIT 32

// ---------------- SGEMM: C[M,N] = A[M,K] @ B[K,N], row-major fp32 ----------------
// Requires M%128==0, N%128==0, K%8==0. blockIdx.z = batch; per-batch strides in elements.
__global__ __launch_bounds__(256)
void sgemm_kernel(const float* __restrict__ A, const float* __restrict__ B,
                  float* __restrict__ C, int M, int N, int K,
                  long Abs, long Bbs, long Cbs)
{
    const int b = blockIdx.z;
    A += (long)b * Abs; B += (long)b * Bbs; C += (long)b * Cbs;
    __shared__ float As[8][132];   // padded to dodge bank conflicts on transposed store
    __shared__ float Bs[8][128];
    const int tid = threadIdx.x;
    const int bm = blockIdx.y * 128, bn = blockIdx.x * 128;
    const int tr = (tid >> 4) & 15, tc = tid & 15;

    float acc[8][8];
#pragma unroll
    for (int i = 0; i < 8; ++i)
#pragma unroll
        for (int j = 0; j < 8; ++j) acc[i][j] = 0.f;

    const int lm = tid >> 1, lk = (tid & 1) * 4;      // A-tile load coords
    const int bk = tid >> 5, bn4 = (tid & 31) * 4;    // B-tile load coords

    for (int kt = 0; kt < K; kt += 8) {
        __syncthreads();
        float4 av = *(const float4*)(A + (long)(bm + lm) * K + kt + lk);
        float4 bv = *(const float4*)(B + (long)(kt + bk) * N + bn + bn4);
        As[lk + 0][lm] = av.x; As[lk + 1][lm] = av.y;
        As[lk + 2][lm] = av.z; As[lk + 3][lm] = av.w;
        *(float4*)&Bs[bk][bn4] = bv;
        __syncthreads();
#pragma unroll
        for (int k = 0; k < 8; ++k) {
            float4 a0 = *(const float4*)&As[k][tr * 4];
            float4 a1 = *(const float4*)&As[k][64 + tr * 4];
            float4 b0 = *(const float4*)&Bs[k][tc * 4];
            float4 b1 = *(const float4*)&Bs[k][64 + tc * 4];
            float avr[8] = {a0.x, a0.y, a0.z, a0.w, a1.x, a1.y, a1.z, a1.w};
            float bvr[8] = {b0.x, b0.y, b0.z, b0.w, b1.x, b1.y, b1.z, b1.w};
#pragma unroll
            for (int i = 0; i < 8; ++i)
#pragma unroll
                for (int j = 0; j < 8; ++j)
                    acc[i][j] = fmaf(avr[i], bvr[j], acc[i][j]);
        }
    }
#pragma unroll
    for (int i = 0; i < 8; ++i) {
        int r = bm + ((i < 4) ? tr * 4 + i : 64 + tr * 4 + (i - 4));
        float4 lo = {acc[i][0], acc[i][1], acc[i][2], acc[i][3]};
        float4 hi = {acc[i][4], acc[i][5], acc[i][6], acc[i][7]};
        *(float4*)(C + (long)r * N + bn + tc * 4) = lo;
        *(float4*)(C + (long)r * N + bn + 64 + tc * 4) = hi;
    }
}

// ---------------- depthwise 3x3, pad 1 ----------------
__global__ __launch_bounds__(256)
void dwconv_kernel(const float* __restrict__ in, const float* __restrict__ w,
                   float* __restrict__ out)
{
    const long base = (long)blockIdx.y * QKVC * HW;
    const int idx = blockIdx.x * 256 + threadIdx.x;      // channel*HW + pixel
    const int ch = idx >> 14, p = idx & 16383;
    const int y = p >> 7, x = p & 127;
    const float* wp = w + ch * 9;
    const float* ip = in + base + (long)ch * HW;
    float s = 0.f;
#pragma unroll
    for (int dy = -1; dy <= 1; ++dy) {
        int yy = y + dy;
        if ((unsigned)yy >= 128u) continue;
#pragma unroll
        for (int dx = -1; dx <= 1; ++dx) {
            int xx = x + dx;
            if ((unsigned)xx >= 128u) continue;
            s = fmaf(wp[(dy + 1) * 3 + (dx + 1)], ip[yy * WIDTH + xx], s);
        }
    }
    out[base + p + (long)ch * HW] = s;
}

// ---------------- inverse L2 norms of q,k rows (channels 0..767) ----------------
__global__ __launch_bounds__(256)
void norm_kernel(const float* __restrict__ dw, float* __restrict__ inv)
{
    const int r = blockIdx.x;          // 0..767
    const int b = blockIdx.y;
    const float* row = dw + ((long)b * QKVC + r) * HW;
    float ss = 0.f;
    for (int i = threadIdx.x; i < HW / 4; i += 256) {
        float4 v = ((const float4*)row)[i];
        ss += v.x * v.x + v.y * v.y + v.z * v.z + v.w * v.w;
    }
    __shared__ float red[4];
    for (int o = 32; o > 0; o >>= 1) ss += __shfl_down(ss, o);
    if ((threadIdx.x & 63) == 0) red[threadIdx.x >> 6] = ss;
    __syncthreads();
    if (threadIdx.x == 0) {
        float t = red[0] + red[1] + red[2] + red[3];
        inv[(long)b * 768 + r] = 1.f / fmaxf(sqrtf(t), 1e-12f);
    }
}

// ---------------- attn partial: per (split,head,b) 48x48 dot over 512 cols ----------------
__global__ __launch_bounds__(256)
void attn_partial_kernel(const float* __restrict__ dw, float* __restrict__ part)
{
    const int split = blockIdx.x, h = blockIdx.y, b = blockIdx.z;
    const int n0 = split * (HW / NSPLIT);
    const float* qbase = dw + ((long)b * QKVC + h * CH) * HW;
    const float* kbase = dw + ((long)b * QKVC + CDIM + h * CH) * HW;
    __shared__ float qs[64][CH];
    __shared__ float ks[64][CH];
    const int tid = threadIdx.x;
    const int tr = tid >> 4, tc = tid & 15;
    const int c0 = tr * 3, d0 = tc * 3;
    float acc[3][3] = {{0.f}};
    for (int ns = 0; ns < HW / NSPLIT; ns += 64) {
        __syncthreads();
        for (int li = tid; li < CH * 16; li += 256) {
            int c = li >> 4, nq = (li & 15) * 4;
            float4 qv = *(const float4*)(qbase + (long)c * HW + n0 + ns + nq);
            float4 kv = *(const float4*)(kbase + (long)c * HW + n0 + ns + nq);
            qs[nq + 0][c] = qv.x; qs[nq + 1][c] = qv.y;
            qs[nq + 2][c] = qv.z; qs[nq + 3][c] = qv.w;
            ks[nq + 0][c] = kv.x; ks[nq + 1][c] = kv.y;
            ks[nq + 2][c] = kv.z; ks[nq + 3][c] = kv.w;
        }
        __syncthreads();
#pragma unroll 8
        for (int n = 0; n < 64; ++n) {
            float q0 = qs[n][c0], q1 = qs[n][c0 + 1], q2 = qs[n][c0 + 2];
            float k0 = ks[n][d0], k1 = ks[n][d0 + 1], k2 = ks[n][d0 + 2];
            acc[0][0] = fmaf(q0, k0, acc[0][0]); acc[0][1] = fmaf(q0, k1, acc[0][1]); acc[0][2] = fmaf(q0, k2, acc[0][2]);
            acc[1][0] = fmaf(q1, k0, acc[1][0]); acc[1][1] = fmaf(q1, k1, acc[1][1]); acc[1][2] = fmaf(q1, k2, acc[1][2]);
            acc[2][0] = fmaf(q2, k0, acc[2][0]); acc[2][1] = fmaf(q2, k1, acc[2][1]); acc[2][2] = fmaf(q2, k2, acc[2][2]);
        }
    }
    float* po = part + (((long)b * HEADS + h) * NSPLIT + split) * (CH * CH);
#pragma unroll
    for (int i = 0; i < 3; ++i)
#pragma unroll
        for (int j = 0; j < 3; ++j)
            po[(c0 + i) * CH + d0 + j] = acc[i][j];
}

// ---------------- attn reduce + apply inv-norms + temperature ----------------
__global__ __launch_bounds__(256)
void attn_reduce_kernel(const float* __restrict__ part, const float* __restrict__ inv,
                        const float* __restrict__ temp, float* __restrict__ attn)
{
    const int h = blockIdx.x, b = blockIdx.y;
    const float* pp = part + (((long)b * HEADS + h) * NSPLIT) * (CH * CH);
    const float t = temp[h];
    for (int idx = threadIdx.x; idx < CH * CH; idx += 256) {
        int c = idx / CH, d = idx % CH;
        float s = 0.f;
        for (int sp = 0; sp < NSPLIT; ++sp) s += pp[sp * CH * CH + idx];
        float iq = inv[(long)b * 768 + h * CH + c];
        float ik = inv[(long)b * 768 + CDIM + h * CH + d];
        attn[((long)b * HEADS + h) * (CH * CH) + idx] = s * iq * ik * t;
    }
}

// ---------------- two-stage masked softmax -> combined weights W ----------------
// Stage i: keep entries with stable rank < kk (matches lax.top_k tie-by-lowest-index),
// softmax over kept (others exactly 0). Stage 2 runs on stage-1's softmax output.
// W = attns[0]*A1 + attns[1]*A2.
__global__ __launch_bounds__(64)
void maskw_kernel(const float* __restrict__ attn, const float* __restrict__ attns,
                  float* __restrict__ W)
{
    const int h = blockIdx.x, b = blockIdx.y;
    __shared__ float sA[48][48];
    __shared__ float sB[48][48];
    const float* ap = attn + ((long)b * HEADS + h) * (CH * CH);
    for (int i = threadIdx.x; i < CH * CH; i += 64) sA[i / 48][i % 48] = ap[i];
    __syncthreads();
    const int r = threadIdx.x;
    if (r < 48) {
        // ---- pass 1: kk = 24 ----
        unsigned long long keep = 0ull;
        for (int i = 0; i < 48; ++i) {
            float ai = sA[r][i];
            int rank = 0;
            for (int j = 0; j < 48; ++j) {
                float aj = sA[r][j];
                rank += (aj > ai) || (aj == ai && j < i);
            }
            if (rank < 24) keep |= 1ull << i;
        }
        float m = -3.4e38f;
        for (int i = 0; i < 48; ++i)
            if ((keep >> i) & 1) m = fmaxf(m, sA[r][i]);
        float s = 0.f;
        for (int i = 0; i < 48; ++i) {
            float e = ((keep >> i) & 1) ? expf(sA[r][i] - m) : 0.f;
            sB[r][i] = e; s += e;
        }
        float is = 1.f / s;
        for (int i = 0; i < 48; ++i) sB[r][i] *= is;   // A1 (exact zeros where masked)
        // ---- pass 2 on A1: kk = 36 ----
        unsigned long long keep2 = 0ull;
        for (int i = 0; i < 48; ++i) {
            float ai = sB[r][i];
            int rank = 0;
            for (int j = 0; j < 48; ++j) {
                float aj = sB[r][j];
                rank += (aj > ai) || (aj == ai && j < i);
            }
            if (rank < 36) keep2 |= 1ull << i;
        }
        float m2 = -3.4e38f;
        for (int i = 0; i < 48; ++i)
            if ((keep2 >> i) & 1) m2 = fmaxf(m2, sB[r][i]);
        float s2 = 0.f;
        for (int i = 0; i < 48; ++i) {
            float e = ((keep2 >> i) & 1) ? expf(sB[r][i] - m2) : 0.f;
            sA[r][i] = e; s2 += e;
        }
        float w0 = attns[0], w1 = attns[1], is2 = 1.f / s2;
        for (int i = 0; i < 48; ++i) sA[r][i] = w0 * sB[r][i] + w1 * (sA[r][i] * is2);
    }
    __syncthreads();
    float* wp = W + ((long)b * HEADS + h) * (CH * CH);
    for (int i = threadIdx.x; i < CH * CH; i += 64) wp[i] = sA[i / 48][i % 48];
}

// ---------------- M = P @ blockdiag(W): M[o][h*48+d] = sum_c P[o][h*48+c]*W[h][c][d] ----------------
__global__ __launch_bounds__(256)
void mbuild_kernel(const float* __restrict__ P, const float* __restrict__ W,
                   float* __restrict__ M)
{
    const int b = blockIdx.y;
    const int idx = blockIdx.x * 256 + threadIdx.x;     // over 384*384
    const int o = idx / CDIM, col = idx % CDIM;
    const int h = col / CH, d = col % CH;
    const float* wp = W + ((long)b * HEADS + h) * (CH * CH) + d;
    const float* pp = P + (long)o * CDIM + h * CH;
    float s = 0.f;
#pragma unroll
    for (int c = 0; c < CH; ++c) s = fmaf(pp[c], wp[c * CH], s);
    M[(long)b * CDIM * CDIM + idx] = s;
}

extern "C" void kernel_launch(void* const* d_in, const int* in_sizes, int n_in,
                              void* d_out, int out_size, void* d_ws, size_t ws_size,
                              hipStream_t stream)
{
    const float* x      = (const float*)d_in[0];
    const float* qkv_w  = (const float*)d_in[1];
    const float* dw_w   = (const float*)d_in[2];
    const float* proj_w = (const float*)d_in[3];
    const float* temp   = (const float*)d_in[4];
    const float* attns  = (const float*)d_in[5];
    float* out = (float*)d_out;

    const size_t perb = (size_t)QKVC * HW;   // elements of pre/dw per batch
    auto need = [&](int nb) -> size_t {
        return sizeof(float) * (2 * perb * (size_t)nb + 768u * nb
               + (size_t)nb * HEADS * NSPLIT * CH * CH
               + 2ull * nb * HEADS * CH * CH
               + (size_t)nb * CDIM * CDIM);
    };
    int NB = 4;
    while (NB > 1 && need(NB) > ws_size) NB >>= 1;

    for (int b0 = 0; b0 < 4; b0 += NB) {
        const int nb = NB;
        float* pre  = (float*)d_ws;
        float* dwb  = pre + perb * nb;
        float* inv  = dwb + perb * nb;
        float* part = inv + 768 * (size_t)nb;
        float* attn = part + (size_t)nb * HEADS * NSPLIT * CH * CH;
        float* Wm   = attn + (size_t)nb * HEADS * CH * CH;
        float* Mm   = Wm + (size_t)nb * HEADS * CH * CH;

        // 1) qkv 1x1 conv: pre[b] = qkv_w @ x[b]
        dim3 g1(HW / 128, QKVC / 128, nb);
        sgemm_kernel<<<g1, 256, 0, stream>>>(qkv_w, x + (size_t)b0 * CDIM * HW, pre,
                                             QKVC, HW, CDIM,
                                             0L, (long)CDIM * HW, (long)QKVC * HW);
        // 2) depthwise 3x3
        dwconv_kernel<<<dim3(QKVC * HW / 256, nb), 256, 0, stream>>>(pre, dw_w, dwb);
        // 3) inverse norms for q,k
        norm_kernel<<<dim3(768, nb), 256, 0, stream>>>(dwb, inv);
        // 4) attn partials
        attn_partial_kernel<<<dim3(NSPLIT, HEADS, nb), 256, 0, stream>>>(dwb, part);
        // 5) reduce + scale
        attn_reduce_kernel<<<dim3(HEADS, nb), 256, 0, stream>>>(part, inv, temp, attn);
        // 6) two-stage masked softmax -> W
        maskw_kernel<<<dim3(HEADS, nb), 64, 0, stream>>>(attn, attns, Wm);
        // 7) M = proj @ blockdiag(W)
        mbuild_kernel<<<dim3(CDIM * CDIM / 256, nb), 256, 0, stream>>>(proj_w, Wm, Mm);
        // 8) out[b] = M[b] @ v[b]
        dim3 g8(HW / 128, CDIM / 128, nb);
        sgemm_kernel<<<g8, 256, 0, stream>>>(Mm, dwb + (size_t)2 * CDIM * HW,
                                             out + (size_t)b0 * CDIM * HW,
                                             CDIM, HW, CDIM,
                                             (long)CDIM * CDIM, (long)QKVC * HW, (long)CDIM * HW);
    }
}

// Round 2
// 1178.469 us; speedup vs baseline: 1.5032x; 1.5032x over previous
//
#include <hip/hip_runtime.h>
#include <math.h>

#define HW     16384
#define WIDTH  128
#define CDIM   384
#define QKVC   1152
#define HEADS  8
#define CH     48
#define NSPLIT 32
#define GK     384

typedef unsigned short u16;
typedef short bf16x8 __attribute__((ext_vector_type(8)));
typedef float f32x4 __attribute__((ext_vector_type(4)));

// ---- fp32 -> bf16 hi/lo split (RNE both) ----
__device__ __forceinline__ void split2(float x, u16& h, u16& l) {
    union { float f; unsigned u; } a, b, c;
    a.f = x;
    unsigned hu = (a.u + 0x7fffu + ((a.u >> 16) & 1u)) & 0xffff0000u;
    b.u = hu;
    h = (u16)(hu >> 16);
    c.f = x - b.f;
    l = (u16)((c.u + 0x7fffu + ((c.u >> 16) & 1u)) >> 16);
}

__device__ __forceinline__ void gload16(const void* g, void* l) {
    __builtin_amdgcn_global_load_lds((const __attribute__((address_space(1))) unsigned int*)g,
                                     (__attribute__((address_space(3))) unsigned int*)l, 16, 0, 0);
}

// ---------------- MFMA split-bf16 GEMM ----------------
// C[M,HW] fp32 = A[M,384] @ B[384,HW], A given as row-major bf16 hi/lo planes,
// B given TRANSPOSED as Bt[HW,384] bf16 hi/lo planes. Tiles: BM=128 BN=256 BK=32,
// 512 thr (8 waves, 2x4), double-buffered LDS (96KB dynamic), 2-phase schedule.
// LDS XOR swizzle: byte bits4-5 ^= row bits1-2 (involution); applied on the
// global source for global_load_lds (linear dest) and on ds_read addresses.
__global__ __launch_bounds__(512)
void mfma_gemm(const u16* __restrict__ Ah, const u16* __restrict__ Al,
               const u16* __restrict__ Bh, const u16* __restrict__ Bl,
               float* __restrict__ C, int nmb,
               long abs_, long bbs, long cbs)
{
    extern __shared__ char smem[];
    // XCD-chunked swizzle: each XCD gets contiguous n-columns; the m-blocks
    // sharing a B-tile land consecutively on the same XCD (L2 reuse).
    const int tot = gridDim.x * gridDim.y;         // multiple of 8
    const int per = tot >> 3;
    const int fl  = blockIdx.x + gridDim.x * blockIdx.y;
    const int f2  = (fl & 7) * per + (fl >> 3);
    const int nblk = f2 / nmb, mblk = f2 % nmb;
    const int b = blockIdx.z;
    Ah += (long)b * abs_; Al += (long)b * abs_;
    Bh += (long)b * bbs;  Bl += (long)b * bbs;
    C  += (long)b * cbs;
    const int m0 = mblk * 128, n0 = nblk * 256;

    const int tid  = threadIdx.x;
    const int wave = tid >> 6, lane = tid & 63;
    const int lr = lane & 15, lg = lane >> 4;
    const int wm = wave >> 2, wn = wave & 3;       // 2 x 4 wave grid
    const int wb = wave * 1024;                    // wave's 64*16B slice

    // staging coords: thread covers one 16B chunk of one row
    const int sr  = tid >> 2;                      // row 0..127
    const int kxs = (tid & 3) ^ ((sr >> 1) & 3);   // swizzled chunk in source

    f32x4 acc[4][4];
#pragma unroll
    for (int i = 0; i < 4; ++i)
#pragma unroll
        for (int j = 0; j < 4; ++j) acc[i][j] = (f32x4){0.f, 0.f, 0.f, 0.f};

    // plane byte offsets inside one 48KB buffer: Ah 0, Al 8K, Bh 16K(16KB), Bl 32K
#define STAGE(bufsel, kt) do {                                                     \
        char* L = smem + (bufsel) * 49152;                                         \
        const long ko = (long)(kt) * 32 + kxs * 8;                                 \
        gload16(Ah + (long)(m0 + sr) * GK + ko,        L + wb);                    \
        gload16(Al + (long)(m0 + sr) * GK + ko,        L + 8192  + wb);            \
        gload16(Bh + (long)(n0 + sr) * GK + ko,        L + 16384 + wb);            \
        gload16(Bh + (long)(n0 + 128 + sr) * GK + ko,  L + 24576 + wb);            \
        gload16(Bl + (long)(n0 + sr) * GK + ko,        L + 32768 + wb);            \
        gload16(Bl + (long)(n0 + 128 + sr) * GK + ko,  L + 40960 + wb);            \
    } while (0)

    STAGE(0, 0);
    __syncthreads();
    int cur = 0;
    for (int kt = 0; kt < GK / 32; ++kt) {
        if (kt + 1 < GK / 32) STAGE(cur ^ 1, kt + 1);
        const char* L = smem + cur * 49152;
        bf16x8 af[4][2], bf[4][2];
#pragma unroll
        for (int mi = 0; mi < 4; ++mi) {
            int r = wm * 64 + mi * 16 + lr;
            int off = r * 64 + (((lg ^ (r >> 1)) & 3) << 4);
            af[mi][0] = *(const bf16x8*)(L + off);
            af[mi][1] = *(const bf16x8*)(L + 8192 + off);
        }
#pragma unroll
        for (int ni = 0; ni < 4; ++ni) {
            int r = wn * 64 + ni * 16 + lr;
            int off = r * 64 + (((lg ^ (r >> 1)) & 3) << 4);
            bf[ni][0] = *(const bf16x8*)(L + 16384 + off);
            bf[ni][1] = *(const bf16x8*)(L + 32768 + off);
        }
        __builtin_amdgcn_s_setprio(1);
#pragma unroll
        for (int mi = 0; mi < 4; ++mi)
#pragma unroll
            for (int ni = 0; ni < 4; ++ni) {
                acc[mi][ni] = __builtin_amdgcn_mfma_f32_16x16x32_bf16(af[mi][0], bf[ni][0], acc[mi][ni], 0, 0, 0);
                acc[mi][ni] = __builtin_amdgcn_mfma_f32_16x16x32_bf16(af[mi][0], bf[ni][1], acc[mi][ni], 0, 0, 0);
                acc[mi][ni] = __builtin_amdgcn_mfma_f32_16x16x32_bf16(af[mi][1], bf[ni][0], acc[mi][ni], 0, 0, 0);
            }
        __builtin_amdgcn_s_setprio(0);
        __syncthreads();
        cur ^= 1;
    }
#undef STAGE

#pragma unroll
    for (int mi = 0; mi < 4; ++mi)
#pragma unroll
        for (int ni = 0; ni < 4; ++ni) {
            int row = m0 + wm * 64 + mi * 16 + lg * 4;
            int col = n0 + wn * 64 + ni * 16 + lr;
            float* cp = C + (long)row * HW + col;
            cp[0]          = acc[mi][ni][0];
            cp[(long)HW]   = acc[mi][ni][1];
            cp[2L * HW]    = acc[mi][ni][2];
            cp[3L * HW]    = acc[mi][ni][3];
        }
}

// ---------------- transpose + split convert: [384][HW] fp32 -> [HW][384] bf16 hi/lo ----
__global__ __launch_bounds__(256)
void convT_kernel(const float* __restrict__ in, u16* __restrict__ oh, u16* __restrict__ ol,
                  long ibs, long obs)
{
    const int b = blockIdx.z;
    in += (long)b * ibs; oh += (long)b * obs; ol += (long)b * obs;
    __shared__ float t[32][33];
    const int p0 = blockIdx.x * 32, c0 = blockIdx.y * 32;
    const int ty = threadIdx.x >> 5, tx = threadIdx.x & 31;
#pragma unroll
    for (int it = 0; it < 4; ++it) {
        int c = ty + it * 8;
        t[c][tx] = in[(long)(c0 + c) * HW + p0 + tx];
    }
    __syncthreads();
#pragma unroll
    for (int it = 0; it < 4; ++it) {
        int p = ty + it * 8;
        u16 h, l;
        split2(t[tx][p], h, l);
        long o = (long)(p0 + p) * CDIM + c0 + tx;
        oh[o] = h; ol[o] = l;
    }
}

// ---------------- elementwise split convert (qkv_w) ----------------
__global__ __launch_bounds__(256)
void convA_kernel(const float* __restrict__ in, u16* __restrict__ oh, u16* __restrict__ ol, int n)
{
    int i = blockIdx.x * 256 + threadIdx.x;
    if (i < n) split2(in[i], oh[i], ol[i]);
}

// ---------------- depthwise 3x3, pad 1 ----------------
__global__ __launch_bounds__(256)
void dwconv_kernel(const float* __restrict__ in, const float* __restrict__ w,
                   float* __restrict__ out)
{
    const long base = (long)blockIdx.y * QKVC * HW;
    const int idx = blockIdx.x * 256 + threadIdx.x;
    const int ch = idx >> 14, p = idx & 16383;
    const int y = p >> 7, x = p & 127;
    const float* wp = w + ch * 9;
    const float* ip = in + base + (long)ch * HW;
    float s = 0.f;
#pragma unroll
    for (int dy = -1; dy <= 1; ++dy) {
        int yy = y + dy;
        if ((unsigned)yy >= 128u) continue;
#pragma unroll
        for (int dx = -1; dx <= 1; ++dx) {
            int xx = x + dx;
            if ((unsigned)xx >= 128u) continue;
            s = fmaf(wp[(dy + 1) * 3 + (dx + 1)], ip[yy * WIDTH + xx], s);
        }
    }
    out[base + p + (long)ch * HW] = s;
}

// ---------------- inverse L2 norms of q,k rows ----------------
__global__ __launch_bounds__(256)
void norm_kernel(const float* __restrict__ dw, float* __restrict__ inv, long invs)
{
    const int r = blockIdx.x;          // 0..767
    const int b = blockIdx.y;
    const float* row = dw + ((long)b * QKVC + r) * HW;
    float ss = 0.f;
    for (int i = threadIdx.x; i < HW / 4; i += 256) {
        float4 v = ((const float4*)row)[i];
        ss += v.x * v.x + v.y * v.y + v.z * v.z + v.w * v.w;
    }
    __shared__ float red[4];
    for (int o = 32; o > 0; o >>= 1) ss += __shfl_down(ss, o);
    if ((threadIdx.x & 63) == 0) red[threadIdx.x >> 6] = ss;
    __syncthreads();
    if (threadIdx.x == 0) {
        float t = red[0] + red[1] + red[2] + red[3];
        inv[(long)b * invs + r] = 1.f / fmaxf(sqrtf(t), 1e-12f);
    }
}

// ---------------- attn partial: per (split,head,b) 48x48 dot ----------------
__global__ __launch_bounds__(256)
void attn_partial_kernel(const float* __restrict__ dw, float* __restrict__ part, long ps)
{
    const int split = blockIdx.x, h = blockIdx.y, b = blockIdx.z;
    const int n0 = split * (HW / NSPLIT);
    const float* qbase = dw + ((long)b * QKVC + h * CH) * HW;
    const float* kbase = dw + ((long)b * QKVC + CDIM + h * CH) * HW;
    __shared__ float qs[64][CH];
    __shared__ float ks[64][CH];
    const int tid = threadIdx.x;
    const int tr = tid >> 4, tc = tid & 15;
    const int c0 = tr * 3, d0 = tc * 3;
    float acc[3][3] = {{0.f}};
    for (int ns = 0; ns < HW / NSPLIT; ns += 64) {
        __syncthreads();
        for (int li = tid; li < CH * 16; li += 256) {
            int c = li >> 4, nq = (li & 15) * 4;
            float4 qv = *(const float4*)(qbase + (long)c * HW + n0 + ns + nq);
            float4 kv = *(const float4*)(kbase + (long)c * HW + n0 + ns + nq);
            qs[nq + 0][c] = qv.x; qs[nq + 1][c] = qv.y;
            qs[nq + 2][c] = qv.z; qs[nq + 3][c] = qv.w;
            ks[nq + 0][c] = kv.x; ks[nq + 1][c] = kv.y;
            ks[nq + 2][c] = kv.z; ks[nq + 3][c] = kv.w;
        }
        __syncthreads();
#pragma unroll 8
        for (int n = 0; n < 64; ++n) {
            float q0 = qs[n][c0], q1 = qs[n][c0 + 1], q2 = qs[n][c0 + 2];
            float k0 = ks[n][d0], k1 = ks[n][d0 + 1], k2 = ks[n][d0 + 2];
            acc[0][0] = fmaf(q0, k0, acc[0][0]); acc[0][1] = fmaf(q0, k1, acc[0][1]); acc[0][2] = fmaf(q0, k2, acc[0][2]);
            acc[1][0] = fmaf(q1, k0, acc[1][0]); acc[1][1] = fmaf(q1, k1, acc[1][1]); acc[1][2] = fmaf(q1, k2, acc[1][2]);
            acc[2][0] = fmaf(q2, k0, acc[2][0]); acc[2][1] = fmaf(q2, k1, acc[2][1]); acc[2][2] = fmaf(q2, k2, acc[2][2]);
        }
    }
    float* po = part + (long)b * ps + ((long)h * NSPLIT + split) * (CH * CH);
#pragma unroll
    for (int i = 0; i < 3; ++i)
#pragma unroll
        for (int j = 0; j < 3; ++j)
            po[(c0 + i) * CH + d0 + j] = acc[i][j];
}

// ---------------- attn reduce + apply inv-norms + temperature ----------------
__global__ __launch_bounds__(256)
void attn_reduce_kernel(const float* __restrict__ part, const float* __restrict__ inv,
                        const float* __restrict__ temp, float* __restrict__ attn,
                        long ps, long invs, long as_)
{
    const int h = blockIdx.x, b = blockIdx.y;
    const float* pp = part + (long)b * ps + (long)h * NSPLIT * (CH * CH);
    const float t = temp[h];
    for (int idx = threadIdx.x; idx < CH * CH; idx += 256) {
        int c = idx / CH, d = idx % CH;
        float s = 0.f;
        for (int sp = 0; sp < NSPLIT; ++sp) s += pp[sp * CH * CH + idx];
        float iq = inv[(long)b * invs + h * CH + c];
        float ik = inv[(long)b * invs + CDIM + h * CH + d];
        attn[(long)b * as_ + (long)h * (CH * CH) + idx] = s * iq * ik * t;
    }
}

// ---------------- two-stage masked softmax -> combined weights W ----------------
__global__ __launch_bounds__(64)
void maskw_kernel(const float* __restrict__ attn, const float* __restrict__ attns,
                  float* __restrict__ W, long as_, long ws_)
{
    const int h = blockIdx.x, b = blockIdx.y;
    __shared__ float sA[48][48];
    __shared__ float sB[48][48];
    const float* ap = attn + (long)b * as_ + (long)h * (CH * CH);
    for (int i = threadIdx.x; i < CH * CH; i += 64) sA[i / 48][i % 48] = ap[i];
    __syncthreads();
    const int r = threadIdx.x;
    if (r < 48) {
        unsigned long long keep = 0ull;
        for (int i = 0; i < 48; ++i) {
            float ai = sA[r][i];
            int rank = 0;
            for (int j = 0; j < 48; ++j) {
                float aj = sA[r][j];
                rank += (aj > ai) || (aj == ai && j < i);
            }
            if (rank < 24) keep |= 1ull << i;
        }
        float m = -3.4e38f;
        for (int i = 0; i < 48; ++i)
            if ((keep >> i) & 1) m = fmaxf(m, sA[r][i]);
        float s = 0.f;
        for (int i = 0; i < 48; ++i) {
            float e = ((keep >> i) & 1) ? expf(sA[r][i] - m) : 0.f;
            sB[r][i] = e; s += e;
        }
        float is = 1.f / s;
        for (int i = 0; i < 48; ++i) sB[r][i] *= is;
        unsigned long long keep2 = 0ull;
        for (int i = 0; i < 48; ++i) {
            float ai = sB[r][i];
            int rank = 0;
            for (int j = 0; j < 48; ++j) {
                float aj = sB[r][j];
                rank += (aj > ai) || (aj == ai && j < i);
            }
            if (rank < 36) keep2 |= 1ull << i;
        }
        float m2 = -3.4e38f;
        for (int i = 0; i < 48; ++i)
            if ((keep2 >> i) & 1) m2 = fmaxf(m2, sB[r][i]);
        float s2 = 0.f;
        for (int i = 0; i < 48; ++i) {
            float e = ((keep2 >> i) & 1) ? expf(sB[r][i] - m2) : 0.f;
            sA[r][i] = e; s2 += e;
        }
        float w0 = attns[0], w1 = attns[1], is2 = 1.f / s2;
        for (int i = 0; i < 48; ++i) sA[r][i] = w0 * sB[r][i] + w1 * (sA[r][i] * is2);
    }
    __syncthreads();
    float* wp = W + (long)b * ws_ + (long)h * (CH * CH);
    for (int i = threadIdx.x; i < CH * CH; i += 64) wp[i] = sA[i / 48][i % 48];
}

// ---------------- M = P @ blockdiag(W), written as bf16 hi/lo planes ----------------
__global__ __launch_bounds__(256)
void mbuild_kernel(const float* __restrict__ P, const float* __restrict__ W,
                   u16* __restrict__ Mh, u16* __restrict__ Ml, long ws_, long ms)
{
    const int b = blockIdx.y;
    const int idx = blockIdx.x * 256 + threadIdx.x;     // over 384*384
    const int o = idx / CDIM, col = idx % CDIM;
    const int h = col / CH, d = col % CH;
    const float* wp = W + (long)b * ws_ + (long)h * (CH * CH) + d;
    const float* pp = P + (long)o * CDIM + h * CH;
    float s = 0.f;
#pragma unroll
    for (int c = 0; c < CH; ++c) s = fmaf(pp[c], wp[c * CH], s);
    u16 hh, ll;
    split2(s, hh, ll);
    Mh[(long)b * ms + idx] = hh;
    Ml[(long)b * ms + idx] = ll;
}

extern "C" void kernel_launch(void* const* d_in, const int* in_sizes, int n_in,
                              void* d_out, int out_size, void* d_ws, size_t ws_size,
                              hipStream_t stream)
{
    const float* x      = (const float*)d_in[0];
    const float* qkv_w  = (const float*)d_in[1];
    const float* dw_w   = (const float*)d_in[2];
    const float* proj_w = (const float*)d_in[3];
    const float* temp   = (const float*)d_in[4];
    const float* attns  = (const float*)d_in[5];
    float* out = (float*)d_out;

    const size_t perbB = (size_t)QKVC * HW * 4;     // 75,497,472 B per batch buffer
    auto need = [&](int nb) -> size_t {
        return (size_t)nb * 2 * perbB + 4u * QKVC * CDIM + 4096;
    };
    int NB = 4;
    while (NB > 1 && need(NB) > ws_size) NB >>= 1;

    const long fstride = (long)(perbB / 4);   // batch stride in floats
    const long ustride = (long)(perbB / 2);   // batch stride in u16

    // per-batch byte offsets inside buf1 slice (pre is dead when these go live)
    const size_t INV_B  = 26u << 20;
    const size_t PART_B = 27u << 20;
    const size_t ATT_B  = 30u << 20;
    const size_t WM_B   = 31u << 20;
    const size_t MH_B   = 32u << 20;
    const size_t ML_B   = 33u << 20;

    char* buf1 = (char*)d_ws;                        // pre, then vt + smalls
    char* buf2 = buf1 + (size_t)NB * perbB;          // xt, then dwb
    u16* Ah = (u16*)(buf2 + (size_t)NB * perbB);
    u16* Al = Ah + (size_t)QKVC * CDIM;

    // qkv_w -> bf16 hi/lo (once)
    convA_kernel<<<dim3((QKVC * CDIM + 255) / 256), 256, 0, stream>>>(qkv_w, Ah, Al, QKVC * CDIM);

    for (int b0 = 0; b0 < 4; b0 += NB) {
        const int nb = NB;
        float* pre = (float*)buf1;
        float* dwb = (float*)buf2;
        u16* xt_h = (u16*)buf2;                u16* xt_l = xt_h + (size_t)HW * CDIM;
        u16* vt_h = (u16*)buf1;                u16* vt_l = vt_h + (size_t)HW * CDIM;
        float* inv  = (float*)(buf1 + INV_B);
        float* part = (float*)(buf1 + PART_B);
        float* attn = (float*)(buf1 + ATT_B);
        float* Wm   = (float*)(buf1 + WM_B);
        u16* Mh = (u16*)(buf1 + MH_B);
        u16* Ml = (u16*)(buf1 + ML_B);

        // 1) x -> xt (transposed bf16 hi/lo), into buf2 (xt dead after qkv GEMM)
        convT_kernel<<<dim3(HW / 32, CDIM / 32, nb), 256, 0, stream>>>(
            x + (size_t)b0 * CDIM * HW, xt_h, xt_l, (long)CDIM * HW, ustride);
        // 2) pre = qkv_w @ x  (MFMA split-bf16)
        mfma_gemm<<<dim3(HW / 256, QKVC / 128, nb), 512, 98304, stream>>>(
            Ah, Al, xt_h, xt_l, pre, QKVC / 128, 0L, ustride, fstride);
        // 3) depthwise 3x3 (overwrites xt with dwb)
        dwconv_kernel<<<dim3(QKVC * HW / 256, nb), 256, 0, stream>>>(pre, dw_w, dwb);
        // 4) inverse norms
        norm_kernel<<<dim3(768, nb), 256, 0, stream>>>(dwb, inv, fstride);
        // 5) attn partials
        attn_partial_kernel<<<dim3(NSPLIT, HEADS, nb), 256, 0, stream>>>(dwb, part, fstride);
        // 6) reduce + scale
        attn_reduce_kernel<<<dim3(HEADS, nb), 256, 0, stream>>>(part, inv, temp, attn,
                                                                fstride, fstride, fstride);
        // 7) two-stage masked softmax -> W
        maskw_kernel<<<dim3(HEADS, nb), 64, 0, stream>>>(attn, attns, Wm, fstride, fstride);
        // 8) M = proj @ blockdiag(W) -> bf16 hi/lo
        mbuild_kernel<<<dim3(CDIM * CDIM / 256, nb), 256, 0, stream>>>(proj_w, Wm, Mh, Ml,
                                                                       fstride, ustride);
        // 9) v -> vt (transposed bf16 hi/lo), into buf1 (pre dead)
        convT_kernel<<<dim3(HW / 32, CDIM / 32, nb), 256, 0, stream>>>(
            dwb + (size_t)2 * CDIM * HW, vt_h, vt_l, fstride, ustride);
        // 10) out = M @ v (MFMA split-bf16)
        mfma_gemm<<<dim3(HW / 256, CDIM / 128, nb), 512, 98304, stream>>>(
            Mh, Ml, vt_h, vt_l, out + (size_t)b0 * CDIM * HW, CDIM / 128,
            ustride, ustride, (long)CDIM * HW);
    }
}

// Round 3
// 936.575 us; speedup vs baseline: 1.8915x; 1.2583x over previous
//
#include <hip/hip_runtime.h>
#include <math.h>

#define HW     16384
#define WIDTH  128
#define CDIM   384
#define QKVC   1152
#define HEADS  8
#define CH     48
#define NSPLIT 32
#define GK     384

typedef unsigned short u16;
typedef short bf16x8 __attribute__((ext_vector_type(8)));
typedef float f32x4 __attribute__((ext_vector_type(4)));

// ---- fp32 -> bf16 hi/lo split (RNE both) ----
__device__ __forceinline__ void split2(float x, u16& h, u16& l) {
    union { float f; unsigned u; } a, b, c;
    a.f = x;
    unsigned hu = (a.u + 0x7fffu + ((a.u >> 16) & 1u)) & 0xffff0000u;
    b.u = hu;
    h = (u16)(hu >> 16);
    c.f = x - b.f;
    l = (u16)((c.u + 0x7fffu + ((c.u >> 16) & 1u)) >> 16);
}

__device__ __forceinline__ void gload16(const void* g, void* l) {
    __builtin_amdgcn_global_load_lds((const __attribute__((address_space(1))) unsigned int*)g,
                                     (__attribute__((address_space(3))) unsigned int*)l, 16, 0, 0);
}

// ---------------- MFMA split-bf16 GEMM ----------------
// C[M,HW] fp32 = A[M,384] @ B[384,HW]; A row-major bf16 hi/lo planes,
// B TRANSPOSED as Bt[HW,384] bf16 hi/lo planes. BM=128 BN=256 BK=32,
// 512 thr (8 waves 2x4), double-buffered LDS, 2-phase schedule.
__global__ __launch_bounds__(512)
void mfma_gemm(const u16* __restrict__ Ah, const u16* __restrict__ Al,
               const u16* __restrict__ Bh, const u16* __restrict__ Bl,
               float* __restrict__ C, int nmb,
               long abs_, long bbs, long cbs)
{
    extern __shared__ char smem[];
    const int tot = gridDim.x * gridDim.y;
    const int per = tot >> 3;
    const int fl  = blockIdx.x + gridDim.x * blockIdx.y;
    const int f2  = (fl & 7) * per + (fl >> 3);
    const int nblk = f2 / nmb, mblk = f2 % nmb;
    const int b = blockIdx.z;
    Ah += (long)b * abs_; Al += (long)b * abs_;
    Bh += (long)b * bbs;  Bl += (long)b * bbs;
    C  += (long)b * cbs;
    const int m0 = mblk * 128, n0 = nblk * 256;

    const int tid  = threadIdx.x;
    const int wave = tid >> 6, lane = tid & 63;
    const int lr = lane & 15, lg = lane >> 4;
    const int wm = wave >> 2, wn = wave & 3;
    const int wb = wave * 1024;

    const int sr  = tid >> 2;
    const int kxs = (tid & 3) ^ ((sr >> 1) & 3);

    f32x4 acc[4][4];
#pragma unroll
    for (int i = 0; i < 4; ++i)
#pragma unroll
        for (int j = 0; j < 4; ++j) acc[i][j] = (f32x4){0.f, 0.f, 0.f, 0.f};

#define STAGE(bufsel, kt) do {                                                     \
        char* L = smem + (bufsel) * 49152;                                         \
        const long ko = (long)(kt) * 32 + kxs * 8;                                 \
        gload16(Ah + (long)(m0 + sr) * GK + ko,        L + wb);                    \
        gload16(Al + (long)(m0 + sr) * GK + ko,        L + 8192  + wb);            \
        gload16(Bh + (long)(n0 + sr) * GK + ko,        L + 16384 + wb);            \
        gload16(Bh + (long)(n0 + 128 + sr) * GK + ko,  L + 24576 + wb);            \
        gload16(Bl + (long)(n0 + sr) * GK + ko,        L + 32768 + wb);            \
        gload16(Bl + (long)(n0 + 128 + sr) * GK + ko,  L + 40960 + wb);            \
    } while (0)

    STAGE(0, 0);
    __syncthreads();
    int cur = 0;
    for (int kt = 0; kt < GK / 32; ++kt) {
        if (kt + 1 < GK / 32) STAGE(cur ^ 1, kt + 1);
        const char* L = smem + cur * 49152;
        bf16x8 af[4][2], bf[4][2];
#pragma unroll
        for (int mi = 0; mi < 4; ++mi) {
            int r = wm * 64 + mi * 16 + lr;
            int off = r * 64 + (((lg ^ (r >> 1)) & 3) << 4);
            af[mi][0] = *(const bf16x8*)(L + off);
            af[mi][1] = *(const bf16x8*)(L + 8192 + off);
        }
#pragma unroll
        for (int ni = 0; ni < 4; ++ni) {
            int r = wn * 64 + ni * 16 + lr;
            int off = r * 64 + (((lg ^ (r >> 1)) & 3) << 4);
            bf[ni][0] = *(const bf16x8*)(L + 16384 + off);
            bf[ni][1] = *(const bf16x8*)(L + 32768 + off);
        }
        __builtin_amdgcn_s_setprio(1);
#pragma unroll
        for (int mi = 0; mi < 4; ++mi)
#pragma unroll
            for (int ni = 0; ni < 4; ++ni) {
                acc[mi][ni] = __builtin_amdgcn_mfma_f32_16x16x32_bf16(af[mi][0], bf[ni][0], acc[mi][ni], 0, 0, 0);
                acc[mi][ni] = __builtin_amdgcn_mfma_f32_16x16x32_bf16(af[mi][0], bf[ni][1], acc[mi][ni], 0, 0, 0);
                acc[mi][ni] = __builtin_amdgcn_mfma_f32_16x16x32_bf16(af[mi][1], bf[ni][0], acc[mi][ni], 0, 0, 0);
            }
        __builtin_amdgcn_s_setprio(0);
        __syncthreads();
        cur ^= 1;
    }
#undef STAGE

#pragma unroll
    for (int mi = 0; mi < 4; ++mi)
#pragma unroll
        for (int ni = 0; ni < 4; ++ni) {
            int row = m0 + wm * 64 + mi * 16 + lg * 4;
            int col = n0 + wn * 64 + ni * 16 + lr;
            float* cp = C + (long)row * HW + col;
            cp[0]          = acc[mi][ni][0];
            cp[(long)HW]   = acc[mi][ni][1];
            cp[2L * HW]    = acc[mi][ni][2];
            cp[3L * HW]    = acc[mi][ni][3];
        }
}

// ---------------- transpose + split convert: [384][HW] fp32 -> [HW][384] bf16 hi/lo ----
__global__ __launch_bounds__(256)
void convT_kernel(const float* __restrict__ in, u16* __restrict__ oh, u16* __restrict__ ol,
                  long ibs, long obs)
{
    const int b = blockIdx.z;
    in += (long)b * ibs; oh += (long)b * obs; ol += (long)b * obs;
    __shared__ float t[32][33];
    const int p0 = blockIdx.x * 32, c0 = blockIdx.y * 32;
    const int ty = threadIdx.x >> 5, tx = threadIdx.x & 31;
#pragma unroll
    for (int it = 0; it < 4; ++it) {
        int c = ty + it * 8;
        t[c][tx] = in[(long)(c0 + c) * HW + p0 + tx];
    }
    __syncthreads();
#pragma unroll
    for (int it = 0; it < 4; ++it) {
        int p = ty + it * 8;
        u16 h, l;
        split2(t[tx][p], h, l);
        long o = (long)(p0 + p) * CDIM + c0 + tx;
        oh[o] = h; ol[o] = l;
    }
}

// ---------------- elementwise split convert (qkv_w) ----------------
__global__ __launch_bounds__(256)
void convA_kernel(const float* __restrict__ in, u16* __restrict__ oh, u16* __restrict__ ol, int n)
{
    int i = blockIdx.x * 256 + threadIdx.x;
    if (i < n) split2(in[i], oh[i], ol[i]);
}

// ---------------- depthwise 3x3, pad 1 — 8 px/thread, float4 loads/stores ----------------
__global__ __launch_bounds__(256)
void dwconv_kernel(const float* __restrict__ in, const float* __restrict__ w,
                   float* __restrict__ out)
{
    const long base = (long)blockIdx.y * QKVC * HW;
    const int idx = blockIdx.x * 256 + threadIdx.x;      // over QKVC*HW/8
    const int ch = idx >> 11;
    const int wi = idx & 2047;
    const int y = wi >> 4, x0 = (wi & 15) * 8;
    const float* wp = w + ch * 9;
    const float* ip = in + base + (long)ch * HW;
    float o[8] = {0.f, 0.f, 0.f, 0.f, 0.f, 0.f, 0.f, 0.f};
#pragma unroll
    for (int dy = -1; dy <= 1; ++dy) {
        int yy = y + dy;
        if ((unsigned)yy >= 128u) continue;
        const float* rp = ip + yy * WIDTH + x0;
        float4 a  = *(const float4*)rp;
        float4 bq = *(const float4*)(rp + 4);
        float v[10] = { (x0 > 0) ? rp[-1] : 0.f,
                        a.x, a.y, a.z, a.w, bq.x, bq.y, bq.z, bq.w,
                        (x0 < 120) ? rp[8] : 0.f };
        float w0 = wp[(dy + 1) * 3], w1 = wp[(dy + 1) * 3 + 1], w2 = wp[(dy + 1) * 3 + 2];
#pragma unroll
        for (int j = 0; j < 8; ++j)
            o[j] = fmaf(w0, v[j], fmaf(w1, v[j + 1], fmaf(w2, v[j + 2], o[j])));
    }
    float* op = out + base + (long)ch * HW + y * WIDTH + x0;
    *(float4*)op       = (float4){o[0], o[1], o[2], o[3]};
    *(float4*)(op + 4) = (float4){o[4], o[5], o[6], o[7]};
}

// ---------------- attn partial: 48x48 dots over 512-px slice + q/k sumsq partials ----
__global__ __launch_bounds__(256)
void attn_partial_kernel(const float* __restrict__ dw, float* __restrict__ part,
                         float* __restrict__ part2, long ps, long p2s)
{
    const int split = blockIdx.x, h = blockIdx.y, b = blockIdx.z;
    const int n0 = split * (HW / NSPLIT);
    const float* qbase = dw + ((long)b * QKVC + h * CH) * HW;
    const float* kbase = dw + ((long)b * QKVC + CDIM + h * CH) * HW;
    __shared__ float qs[64][CH];
    __shared__ float ks[64][CH];
    const int tid = threadIdx.x;
    const int tr = tid >> 4, tc = tid & 15;
    const int c0 = tr * 3, d0 = tc * 3;
    float acc[3][3] = {{0.f}};
    float qss[3] = {0.f, 0.f, 0.f}, kss[3] = {0.f, 0.f, 0.f};
    const int cA = tid >> 4;                 // rows this thread stages: cA, cA+16, cA+32
    const int nq = (tid & 15) * 4;
    for (int ns = 0; ns < HW / NSPLIT; ns += 64) {
        __syncthreads();
#pragma unroll
        for (int t = 0; t < 3; ++t) {
            int c = cA + t * 16;
            float4 qv = *(const float4*)(qbase + (long)c * HW + n0 + ns + nq);
            float4 kv = *(const float4*)(kbase + (long)c * HW + n0 + ns + nq);
            qs[nq + 0][c] = qv.x; qs[nq + 1][c] = qv.y;
            qs[nq + 2][c] = qv.z; qs[nq + 3][c] = qv.w;
            ks[nq + 0][c] = kv.x; ks[nq + 1][c] = kv.y;
            ks[nq + 2][c] = kv.z; ks[nq + 3][c] = kv.w;
            qss[t] += qv.x * qv.x + qv.y * qv.y + qv.z * qv.z + qv.w * qv.w;
            kss[t] += kv.x * kv.x + kv.y * kv.y + kv.z * kv.z + kv.w * kv.w;
        }
        __syncthreads();
#pragma unroll 8
        for (int n = 0; n < 64; ++n) {
            float q0 = qs[n][c0], q1 = qs[n][c0 + 1], q2 = qs[n][c0 + 2];
            float k0 = ks[n][d0], k1 = ks[n][d0 + 1], k2 = ks[n][d0 + 2];
            acc[0][0] = fmaf(q0, k0, acc[0][0]); acc[0][1] = fmaf(q0, k1, acc[0][1]); acc[0][2] = fmaf(q0, k2, acc[0][2]);
            acc[1][0] = fmaf(q1, k0, acc[1][0]); acc[1][1] = fmaf(q1, k1, acc[1][1]); acc[1][2] = fmaf(q1, k2, acc[1][2]);
            acc[2][0] = fmaf(q2, k0, acc[2][0]); acc[2][1] = fmaf(q2, k1, acc[2][1]); acc[2][2] = fmaf(q2, k2, acc[2][2]);
        }
    }
    // reduce sumsq across the 16 lanes sharing each staged row (lanes grouped by tid>>4)
#pragma unroll
    for (int m = 1; m < 16; m <<= 1) {
#pragma unroll
        for (int t = 0; t < 3; ++t) {
            qss[t] += __shfl_xor(qss[t], m);
            kss[t] += __shfl_xor(kss[t], m);
        }
    }
    if ((tid & 15) == 0) {
        float* p2 = part2 + (long)b * p2s + ((long)h * NSPLIT + split) * 96;
#pragma unroll
        for (int t = 0; t < 3; ++t) {
            p2[cA + t * 16]      = qss[t];
            p2[48 + cA + t * 16] = kss[t];
        }
    }
    float* po = part + (long)b * ps + ((long)h * NSPLIT + split) * (CH * CH);
#pragma unroll
    for (int i = 0; i < 3; ++i)
#pragma unroll
        for (int j = 0; j < 3; ++j)
            po[(c0 + i) * CH + d0 + j] = acc[i][j];
}

// ---------------- attn reduce: sum partials, inv-norms from sumsq, temperature ----
__global__ __launch_bounds__(256)
void attn_reduce_kernel(const float* __restrict__ part, const float* __restrict__ part2,
                        const float* __restrict__ temp, float* __restrict__ attn,
                        long ps, long p2s, long as_)
{
    const int h = blockIdx.x, b = blockIdx.y;
    const float* pp = part + (long)b * ps + (long)h * NSPLIT * (CH * CH);
    const float* p2 = part2 + (long)b * p2s + (long)h * NSPLIT * 96;
    __shared__ float sinv[96];
    if (threadIdx.x < 96) {
        float s = 0.f;
        for (int sp = 0; sp < NSPLIT; ++sp) s += p2[sp * 96 + threadIdx.x];
        sinv[threadIdx.x] = 1.f / fmaxf(sqrtf(s), 1e-12f);
    }
    __syncthreads();
    const float t = temp[h];
    for (int idx = threadIdx.x; idx < CH * CH; idx += 256) {
        int c = idx / CH, d = idx % CH;
        float s = 0.f;
        for (int sp = 0; sp < NSPLIT; ++sp) s += pp[sp * CH * CH + idx];
        attn[(long)b * as_ + (long)h * (CH * CH) + idx] = s * sinv[c] * sinv[48 + d] * t;
    }
}

// ---------------- two-stage masked softmax -> combined weights W ----------------
__global__ __launch_bounds__(64)
void maskw_kernel(const float* __restrict__ attn, const float* __restrict__ attns,
                  float* __restrict__ W, long as_, long ws_)
{
    const int h = blockIdx.x, b = blockIdx.y;
    __shared__ float sA[48][48];
    __shared__ float sB[48][48];
    const float* ap = attn + (long)b * as_ + (long)h * (CH * CH);
    for (int i = threadIdx.x; i < CH * CH; i += 64) sA[i / 48][i % 48] = ap[i];
    __syncthreads();
    const int r = threadIdx.x;
    if (r < 48) {
        unsigned long long keep = 0ull;
        for (int i = 0; i < 48; ++i) {
            float ai = sA[r][i];
            int rank = 0;
            for (int j = 0; j < 48; ++j) {
                float aj = sA[r][j];
                rank += (aj > ai) || (aj == ai && j < i);
            }
            if (rank < 24) keep |= 1ull << i;
        }
        float m = -3.4e38f;
        for (int i = 0; i < 48; ++i)
            if ((keep >> i) & 1) m = fmaxf(m, sA[r][i]);
        float s = 0.f;
        for (int i = 0; i < 48; ++i) {
            float e = ((keep >> i) & 1) ? expf(sA[r][i] - m) : 0.f;
            sB[r][i] = e; s += e;
        }
        float is = 1.f / s;
        for (int i = 0; i < 48; ++i) sB[r][i] *= is;
        unsigned long long keep2 = 0ull;
        for (int i = 0; i < 48; ++i) {
            float ai = sB[r][i];
            int rank = 0;
            for (int j = 0; j < 48; ++j) {
                float aj = sB[r][j];
                rank += (aj > ai) || (aj == ai && j < i);
            }
            if (rank < 36) keep2 |= 1ull << i;
        }
        float m2 = -3.4e38f;
        for (int i = 0; i < 48; ++i)
            if ((keep2 >> i) & 1) m2 = fmaxf(m2, sB[r][i]);
        float s2 = 0.f;
        for (int i = 0; i < 48; ++i) {
            float e = ((keep2 >> i) & 1) ? expf(sB[r][i] - m2) : 0.f;
            sA[r][i] = e; s2 += e;
        }
        float w0 = attns[0], w1 = attns[1], is2 = 1.f / s2;
        for (int i = 0; i < 48; ++i) sA[r][i] = w0 * sB[r][i] + w1 * (sA[r][i] * is2);
    }
    __syncthreads();
    float* wp = W + (long)b * ws_ + (long)h * (CH * CH);
    for (int i = threadIdx.x; i < CH * CH; i += 64) wp[i] = sA[i / 48][i % 48];
}

// ---------------- M = P @ blockdiag(W), written as bf16 hi/lo planes ----------------
__global__ __launch_bounds__(256)
void mbuild_kernel(const float* __restrict__ P, const float* __restrict__ W,
                   u16* __restrict__ Mh, u16* __restrict__ Ml, long ws_, long ms)
{
    const int b = blockIdx.y;
    const int idx = blockIdx.x * 256 + threadIdx.x;
    const int o = idx / CDIM, col = idx % CDIM;
    const int h = col / CH, d = col % CH;
    const float* wp = W + (long)b * ws_ + (long)h * (CH * CH) + d;
    const float* pp = P + (long)o * CDIM + h * CH;
    float s = 0.f;
#pragma unroll
    for (int c = 0; c < CH; ++c) s = fmaf(pp[c], wp[c * CH], s);
    u16 hh, ll;
    split2(s, hh, ll);
    Mh[(long)b * ms + idx] = hh;
    Ml[(long)b * ms + idx] = ll;
}

extern "C" void kernel_launch(void* const* d_in, const int* in_sizes, int n_in,
                              void* d_out, int out_size, void* d_ws, size_t ws_size,
                              hipStream_t stream)
{
    const float* x      = (const float*)d_in[0];
    const float* qkv_w  = (const float*)d_in[1];
    const float* dw_w   = (const float*)d_in[2];
    const float* proj_w = (const float*)d_in[3];
    const float* temp   = (const float*)d_in[4];
    const float* attns  = (const float*)d_in[5];
    float* out = (float*)d_out;

    const size_t perbB = (size_t)QKVC * HW * 4;
    auto need = [&](int nb) -> size_t {
        return (size_t)nb * 2 * perbB + 4u * QKVC * CDIM + 4096;
    };
    int NB = 4;
    while (NB > 1 && need(NB) > ws_size) NB >>= 1;

    const long fstride = (long)(perbB / 4);
    const long ustride = (long)(perbB / 2);

    const size_t PART_B  = 27u << 20;
    const size_t PART2_B = (29u << 20) + (512u << 10);
    const size_t ATT_B   = 30u << 20;
    const size_t WM_B    = 31u << 20;
    const size_t MH_B    = 32u << 20;
    const size_t ML_B    = 33u << 20;

    char* buf1 = (char*)d_ws;
    char* buf2 = buf1 + (size_t)NB * perbB;
    u16* Ah = (u16*)(buf2 + (size_t)NB * perbB);
    u16* Al = Ah + (size_t)QKVC * CDIM;

    convA_kernel<<<dim3((QKVC * CDIM + 255) / 256), 256, 0, stream>>>(qkv_w, Ah, Al, QKVC * CDIM);

    for (int b0 = 0; b0 < 4; b0 += NB) {
        const int nb = NB;
        float* pre = (float*)buf1;
        float* dwb = (float*)buf2;
        u16* xt_h = (u16*)buf2;                u16* xt_l = xt_h + (size_t)HW * CDIM;
        u16* vt_h = (u16*)buf1;                u16* vt_l = vt_h + (size_t)HW * CDIM;
        float* part  = (float*)(buf1 + PART_B);
        float* part2 = (float*)(buf1 + PART2_B);
        float* attn  = (float*)(buf1 + ATT_B);
        float* Wm    = (float*)(buf1 + WM_B);
        u16* Mh = (u16*)(buf1 + MH_B);
        u16* Ml = (u16*)(buf1 + ML_B);

        // 1) x -> xt (transposed bf16 hi/lo)
        convT_kernel<<<dim3(HW / 32, CDIM / 32, nb), 256, 0, stream>>>(
            x + (size_t)b0 * CDIM * HW, xt_h, xt_l, (long)CDIM * HW, ustride);
        // 2) pre = qkv_w @ x  (MFMA split-bf16)
        mfma_gemm<<<dim3(HW / 256, QKVC / 128, nb), 512, 98304, stream>>>(
            Ah, Al, xt_h, xt_l, pre, QKVC / 128, 0L, ustride, fstride);
        // 3) depthwise 3x3 (overwrites xt with dwb)
        dwconv_kernel<<<dim3(QKVC * HW / 8 / 256, nb), 256, 0, stream>>>(pre, dw_w, dwb);
        // 4) attn partials + sumsq partials
        attn_partial_kernel<<<dim3(NSPLIT, HEADS, nb), 256, 0, stream>>>(dwb, part, part2,
                                                                         fstride, fstride);
        // 5) reduce + inv-norms + scale
        attn_reduce_kernel<<<dim3(HEADS, nb), 256, 0, stream>>>(part, part2, temp, attn,
                                                                fstride, fstride, fstride);
        // 6) two-stage masked softmax -> W
        maskw_kernel<<<dim3(HEADS, nb), 64, 0, stream>>>(attn, attns, Wm, fstride, fstride);
        // 7) M = proj @ blockdiag(W) -> bf16 hi/lo
        mbuild_kernel<<<dim3(CDIM * CDIM / 256, nb), 256, 0, stream>>>(proj_w, Wm, Mh, Ml,
                                                                       fstride, ustride);
        // 8) v -> vt (transposed bf16 hi/lo)
        convT_kernel<<<dim3(HW / 32, CDIM / 32, nb), 256, 0, stream>>>(
            dwb + (size_t)2 * CDIM * HW, vt_h, vt_l, fstride, ustride);
        // 9) out = M @ v (MFMA split-bf16)
        mfma_gemm<<<dim3(HW / 256, CDIM / 128, nb), 512, 98304, stream>>>(
            Mh, Ml, vt_h, vt_l, out + (size_t)b0 * CDIM * HW, CDIM / 128,
            ustride, ustride, (long)CDIM * HW);
    }
}

// Round 4
// 698.515 us; speedup vs baseline: 2.5361x; 1.3408x over previous
//
#include <hip/hip_runtime.h>
#include <math.h>

#define HW     16384
#define WIDTH  128
#define CDIM   384
#define QKVC   1152
#define HEADS  8
#define CH     48
#define NSPLIT 32
#define GK     384

typedef unsigned short u16;
typedef short bf16x8 __attribute__((ext_vector_type(8)));
typedef float f32x4 __attribute__((ext_vector_type(4)));

// ---- fp32 -> bf16 hi/lo split (RNE both) ----
__device__ __forceinline__ void split2(float x, u16& h, u16& l) {
    union { float f; unsigned u; } a, b, c;
    a.f = x;
    unsigned hu = (a.u + 0x7fffu + ((a.u >> 16) & 1u)) & 0xffff0000u;
    b.u = hu;
    h = (u16)(hu >> 16);
    c.f = x - b.f;
    l = (u16)((c.u + 0x7fffu + ((c.u >> 16) & 1u)) >> 16);
}

__device__ __forceinline__ void gload16(const void* g, void* l) {
    __builtin_amdgcn_global_load_lds((const __attribute__((address_space(1))) unsigned int*)g,
                                     (__attribute__((address_space(3))) unsigned int*)l, 16, 0, 0);
}

// ---------------- MFMA split-bf16 GEMM ----------------
// C[M,HW] fp32 = A[M,384] @ B[384,HW]; A row-major bf16 hi/lo planes,
// B TRANSPOSED as Bt[HW,384] bf16 hi/lo planes. BM=128 BN=256 BK=32,
// 512 thr (8 waves 2x4), double-buffered LDS, 2-phase schedule.
__global__ __launch_bounds__(512)
void mfma_gemm(const u16* __restrict__ Ah, const u16* __restrict__ Al,
               const u16* __restrict__ Bh, const u16* __restrict__ Bl,
               float* __restrict__ C, int nmb,
               long abs_, long bbs, long cbs)
{
    extern __shared__ char smem[];
    const int tot = gridDim.x * gridDim.y;
    const int per = tot >> 3;
    const int fl  = blockIdx.x + gridDim.x * blockIdx.y;
    const int f2  = (fl & 7) * per + (fl >> 3);
    const int nblk = f2 / nmb, mblk = f2 % nmb;
    const int b = blockIdx.z;
    Ah += (long)b * abs_; Al += (long)b * abs_;
    Bh += (long)b * bbs;  Bl += (long)b * bbs;
    C  += (long)b * cbs;
    const int m0 = mblk * 128, n0 = nblk * 256;

    const int tid  = threadIdx.x;
    const int wave = tid >> 6, lane = tid & 63;
    const int lr = lane & 15, lg = lane >> 4;
    const int wm = wave >> 2, wn = wave & 3;
    const int wb = wave * 1024;

    const int sr  = tid >> 2;
    const int kxs = (tid & 3) ^ ((sr >> 1) & 3);

    f32x4 acc[4][4];
#pragma unroll
    for (int i = 0; i < 4; ++i)
#pragma unroll
        for (int j = 0; j < 4; ++j) acc[i][j] = (f32x4){0.f, 0.f, 0.f, 0.f};

#define STAGE(bufsel, kt) do {                                                     \
        char* L = smem + (bufsel) * 49152;                                         \
        const long ko = (long)(kt) * 32 + kxs * 8;                                 \
        gload16(Ah + (long)(m0 + sr) * GK + ko,        L + wb);                    \
        gload16(Al + (long)(m0 + sr) * GK + ko,        L + 8192  + wb);            \
        gload16(Bh + (long)(n0 + sr) * GK + ko,        L + 16384 + wb);            \
        gload16(Bh + (long)(n0 + 128 + sr) * GK + ko,  L + 24576 + wb);            \
        gload16(Bl + (long)(n0 + sr) * GK + ko,        L + 32768 + wb);            \
        gload16(Bl + (long)(n0 + 128 + sr) * GK + ko,  L + 40960 + wb);            \
    } while (0)

    STAGE(0, 0);
    __syncthreads();
    int cur = 0;
    for (int kt = 0; kt < GK / 32; ++kt) {
        if (kt + 1 < GK / 32) STAGE(cur ^ 1, kt + 1);
        const char* L = smem + cur * 49152;
        bf16x8 af[4][2], bf[4][2];
#pragma unroll
        for (int mi = 0; mi < 4; ++mi) {
            int r = wm * 64 + mi * 16 + lr;
            int off = r * 64 + (((lg ^ (r >> 1)) & 3) << 4);
            af[mi][0] = *(const bf16x8*)(L + off);
            af[mi][1] = *(const bf16x8*)(L + 8192 + off);
        }
#pragma unroll
        for (int ni = 0; ni < 4; ++ni) {
            int r = wn * 64 + ni * 16 + lr;
            int off = r * 64 + (((lg ^ (r >> 1)) & 3) << 4);
            bf[ni][0] = *(const bf16x8*)(L + 16384 + off);
            bf[ni][1] = *(const bf16x8*)(L + 32768 + off);
        }
        __builtin_amdgcn_s_setprio(1);
#pragma unroll
        for (int mi = 0; mi < 4; ++mi)
#pragma unroll
            for (int ni = 0; ni < 4; ++ni) {
                acc[mi][ni] = __builtin_amdgcn_mfma_f32_16x16x32_bf16(af[mi][0], bf[ni][0], acc[mi][ni], 0, 0, 0);
                acc[mi][ni] = __builtin_amdgcn_mfma_f32_16x16x32_bf16(af[mi][0], bf[ni][1], acc[mi][ni], 0, 0, 0);
                acc[mi][ni] = __builtin_amdgcn_mfma_f32_16x16x32_bf16(af[mi][1], bf[ni][0], acc[mi][ni], 0, 0, 0);
            }
        __builtin_amdgcn_s_setprio(0);
        __syncthreads();
        cur ^= 1;
    }
#undef STAGE

#pragma unroll
    for (int mi = 0; mi < 4; ++mi)
#pragma unroll
        for (int ni = 0; ni < 4; ++ni) {
            int row = m0 + wm * 64 + mi * 16 + lg * 4;
            int col = n0 + wn * 64 + ni * 16 + lr;
            float* cp = C + (long)row * HW + col;
            cp[0]          = acc[mi][ni][0];
            cp[(long)HW]   = acc[mi][ni][1];
            cp[2L * HW]    = acc[mi][ni][2];
            cp[3L * HW]    = acc[mi][ni][3];
        }
}

// ---------------- transpose + split convert: [384][HW] fp32 -> [HW][384] bf16 hi/lo ----
__global__ __launch_bounds__(256)
void convT_kernel(const float* __restrict__ in, u16* __restrict__ oh, u16* __restrict__ ol,
                  long ibs, long obs)
{
    const int b = blockIdx.z;
    in += (long)b * ibs; oh += (long)b * obs; ol += (long)b * obs;
    __shared__ float t[32][33];
    const int p0 = blockIdx.x * 32, c0 = blockIdx.y * 32;
    const int ty = threadIdx.x >> 5, tx = threadIdx.x & 31;
#pragma unroll
    for (int it = 0; it < 4; ++it) {
        int c = ty + it * 8;
        t[c][tx] = in[(long)(c0 + c) * HW + p0 + tx];
    }
    __syncthreads();
#pragma unroll
    for (int it = 0; it < 4; ++it) {
        int p = ty + it * 8;
        u16 h, l;
        split2(t[tx][p], h, l);
        long o = (long)(p0 + p) * CDIM + c0 + tx;
        oh[o] = h; ol[o] = l;
    }
}

// ---------------- elementwise split convert (qkv_w) ----------------
__global__ __launch_bounds__(256)
void convA_kernel(const float* __restrict__ in, u16* __restrict__ oh, u16* __restrict__ ol, int n)
{
    int i = blockIdx.x * 256 + threadIdx.x;
    if (i < n) split2(in[i], oh[i], ol[i]);
}

// ---------------- depthwise 3x3, pad 1 — 8 px/thread, float4 loads/stores ----------------
__global__ __launch_bounds__(256)
void dwconv_kernel(const float* __restrict__ in, const float* __restrict__ w,
                   float* __restrict__ out)
{
    const long base = (long)blockIdx.y * QKVC * HW;
    const int idx = blockIdx.x * 256 + threadIdx.x;      // over QKVC*HW/8
    const int ch = idx >> 11;
    const int wi = idx & 2047;
    const int y = wi >> 4, x0 = (wi & 15) * 8;
    const float* wp = w + ch * 9;
    const float* ip = in + base + (long)ch * HW;
    float o[8] = {0.f, 0.f, 0.f, 0.f, 0.f, 0.f, 0.f, 0.f};
#pragma unroll
    for (int dy = -1; dy <= 1; ++dy) {
        int yy = y + dy;
        if ((unsigned)yy >= 128u) continue;
        const float* rp = ip + yy * WIDTH + x0;
        float4 a  = *(const float4*)rp;
        float4 bq = *(const float4*)(rp + 4);
        float v[10] = { (x0 > 0) ? rp[-1] : 0.f,
                        a.x, a.y, a.z, a.w, bq.x, bq.y, bq.z, bq.w,
                        (x0 < 120) ? rp[8] : 0.f };
        float w0 = wp[(dy + 1) * 3], w1 = wp[(dy + 1) * 3 + 1], w2 = wp[(dy + 1) * 3 + 2];
#pragma unroll
        for (int j = 0; j < 8; ++j)
            o[j] = fmaf(w0, v[j], fmaf(w1, v[j + 1], fmaf(w2, v[j + 2], o[j])));
    }
    float* op = out + base + (long)ch * HW + y * WIDTH + x0;
    *(float4*)op       = (float4){o[0], o[1], o[2], o[3]};
    *(float4*)(op + 4) = (float4){o[4], o[5], o[6], o[7]};
}

// ---------------- attn partial: 48x48 dots over 512-px slice + q/k sumsq partials ----
__global__ __launch_bounds__(256)
void attn_partial_kernel(const float* __restrict__ dw, float* __restrict__ part,
                         float* __restrict__ part2, long ps, long p2s)
{
    const int split = blockIdx.x, h = blockIdx.y, b = blockIdx.z;
    const int n0 = split * (HW / NSPLIT);
    const float* qbase = dw + ((long)b * QKVC + h * CH) * HW;
    const float* kbase = dw + ((long)b * QKVC + CDIM + h * CH) * HW;
    __shared__ float qs[64][CH];
    __shared__ float ks[64][CH];
    const int tid = threadIdx.x;
    const int tr = tid >> 4, tc = tid & 15;
    const int c0 = tr * 3, d0 = tc * 3;
    float acc[3][3] = {{0.f}};
    float qss[3] = {0.f, 0.f, 0.f}, kss[3] = {0.f, 0.f, 0.f};
    const int cA = tid >> 4;
    const int nq = (tid & 15) * 4;
    for (int ns = 0; ns < HW / NSPLIT; ns += 64) {
        __syncthreads();
#pragma unroll
        for (int t = 0; t < 3; ++t) {
            int c = cA + t * 16;
            float4 qv = *(const float4*)(qbase + (long)c * HW + n0 + ns + nq);
            float4 kv = *(const float4*)(kbase + (long)c * HW + n0 + ns + nq);
            qs[nq + 0][c] = qv.x; qs[nq + 1][c] = qv.y;
            qs[nq + 2][c] = qv.z; qs[nq + 3][c] = qv.w;
            ks[nq + 0][c] = kv.x; ks[nq + 1][c] = kv.y;
            ks[nq + 2][c] = kv.z; ks[nq + 3][c] = kv.w;
            qss[t] += qv.x * qv.x + qv.y * qv.y + qv.z * qv.z + qv.w * qv.w;
            kss[t] += kv.x * kv.x + kv.y * kv.y + kv.z * kv.z + kv.w * kv.w;
        }
        __syncthreads();
#pragma unroll 8
        for (int n = 0; n < 64; ++n) {
            float q0 = qs[n][c0], q1 = qs[n][c0 + 1], q2 = qs[n][c0 + 2];
            float k0 = ks[n][d0], k1 = ks[n][d0 + 1], k2 = ks[n][d0 + 2];
            acc[0][0] = fmaf(q0, k0, acc[0][0]); acc[0][1] = fmaf(q0, k1, acc[0][1]); acc[0][2] = fmaf(q0, k2, acc[0][2]);
            acc[1][0] = fmaf(q1, k0, acc[1][0]); acc[1][1] = fmaf(q1, k1, acc[1][1]); acc[1][2] = fmaf(q1, k2, acc[1][2]);
            acc[2][0] = fmaf(q2, k0, acc[2][0]); acc[2][1] = fmaf(q2, k1, acc[2][1]); acc[2][2] = fmaf(q2, k2, acc[2][2]);
        }
    }
#pragma unroll
    for (int m = 1; m < 16; m <<= 1) {
#pragma unroll
        for (int t = 0; t < 3; ++t) {
            qss[t] += __shfl_xor(qss[t], m);
            kss[t] += __shfl_xor(kss[t], m);
        }
    }
    if ((tid & 15) == 0) {
        float* p2 = part2 + (long)b * p2s + ((long)h * NSPLIT + split) * 96;
#pragma unroll
        for (int t = 0; t < 3; ++t) {
            p2[cA + t * 16]      = qss[t];
            p2[48 + cA + t * 16] = kss[t];
        }
    }
    float* po = part + (long)b * ps + ((long)h * NSPLIT + split) * (CH * CH);
#pragma unroll
    for (int i = 0; i < 3; ++i)
#pragma unroll
        for (int j = 0; j < 3; ++j)
            po[(c0 + i) * CH + d0 + j] = acc[i][j];
}

// ---------------- attn reduce: sum partials, inv-norms from sumsq, temperature ----
// grid (9, HEADS, nb): 9 x 256 = 2304 = 48*48 entries per (b,h)
__global__ __launch_bounds__(256)
void attn_reduce_kernel(const float* __restrict__ part, const float* __restrict__ part2,
                        const float* __restrict__ temp, float* __restrict__ attn,
                        long ps, long p2s, long as_)
{
    const int seg = blockIdx.x, h = blockIdx.y, b = blockIdx.z;
    const float* pp = part + (long)b * ps + (long)h * NSPLIT * (CH * CH);
    const float* p2 = part2 + (long)b * p2s + (long)h * NSPLIT * 96;
    __shared__ float sinv[96];
    if (threadIdx.x < 96) {
        float s = 0.f;
        for (int sp = 0; sp < NSPLIT; ++sp) s += p2[sp * 96 + threadIdx.x];
        sinv[threadIdx.x] = 1.f / fmaxf(sqrtf(s), 1e-12f);
    }
    __syncthreads();
    const float t = temp[h];
    const int idx = seg * 256 + threadIdx.x;
    const int c = idx / CH, d = idx % CH;
    float s = 0.f;
    for (int sp = 0; sp < NSPLIT; ++sp) s += pp[sp * (CH * CH) + idx];
    attn[(long)b * as_ + (long)h * (CH * CH) + idx] = s * sinv[c] * sinv[48 + d] * t;
}

// ---------------- two-stage masked softmax -> combined weights W ----------------
// Wave-per-row, fully in-register via shuffle broadcast. grid (12, HEADS, nb) x 256.
__global__ __launch_bounds__(256)
void maskw_kernel(const float* __restrict__ attn, const float* __restrict__ attns,
                  float* __restrict__ W, long as_, long ws_)
{
    const int h = blockIdx.y, b = blockIdx.z;
    const int wave = threadIdx.x >> 6, lane = threadIdx.x & 63;
    const int r = blockIdx.x * 4 + wave;                 // 0..47
    const float* ap = attn + (long)b * as_ + (long)h * (CH * CH) + (long)r * CH;
    float a = (lane < CH) ? ap[lane] : -3.4e38f;

    // ---- pass 1: stable rank < 24 (matches top_k tie-by-lowest-index) ----
    int rank = 0;
#pragma unroll
    for (int j = 0; j < CH; ++j) {
        float aj = __shfl(a, j);
        rank += (aj > a) || (aj == a && j < lane);
    }
    const bool keep = (lane < CH) && (rank < 24);
    float m = keep ? a : -3.4e38f;
#pragma unroll
    for (int o = 32; o > 0; o >>= 1) m = fmaxf(m, __shfl_xor(m, o));
    float e = keep ? expf(a - m) : 0.f;
    float s = e;
#pragma unroll
    for (int o = 32; o > 0; o >>= 1) s += __shfl_xor(s, o);
    const float A1 = e / s;                              // exact 0 where masked

    // ---- pass 2 on A1: stable rank < 36 ----
    int rank2 = 0;
#pragma unroll
    for (int j = 0; j < CH; ++j) {
        float aj = __shfl(A1, j);
        rank2 += (aj > A1) || (aj == A1 && j < lane);
    }
    const bool keep2 = (lane < CH) && (rank2 < 36);
    float m2 = keep2 ? A1 : -3.4e38f;
#pragma unroll
    for (int o = 32; o > 0; o >>= 1) m2 = fmaxf(m2, __shfl_xor(m2, o));
    float e2 = keep2 ? expf(A1 - m2) : 0.f;
    float s2 = e2;
#pragma unroll
    for (int o = 32; o > 0; o >>= 1) s2 += __shfl_xor(s2, o);

    if (lane < CH)
        W[(long)b * ws_ + (long)h * (CH * CH) + (long)r * CH + lane] =
            attns[0] * A1 + attns[1] * (e2 / s2);
}

// ---------------- M = P @ blockdiag(W), written as bf16 hi/lo planes ----------------
__global__ __launch_bounds__(256)
void mbuild_kernel(const float* __restrict__ P, const float* __restrict__ W,
                   u16* __restrict__ Mh, u16* __restrict__ Ml, long ws_, long ms)
{
    const int b = blockIdx.y;
    const int idx = blockIdx.x * 256 + threadIdx.x;
    const int o = idx / CDIM, col = idx % CDIM;
    const int h = col / CH, d = col % CH;
    const float* wp = W + (long)b * ws_ + (long)h * (CH * CH) + d;
    const float* pp = P + (long)o * CDIM + h * CH;
    float s = 0.f;
#pragma unroll
    for (int c = 0; c < CH; ++c) s = fmaf(pp[c], wp[c * CH], s);
    u16 hh, ll;
    split2(s, hh, ll);
    Mh[(long)b * ms + idx] = hh;
    Ml[(long)b * ms + idx] = ll;
}

extern "C" void kernel_launch(void* const* d_in, const int* in_sizes, int n_in,
                              void* d_out, int out_size, void* d_ws, size_t ws_size,
                              hipStream_t stream)
{
    const float* x      = (const float*)d_in[0];
    const float* qkv_w  = (const float*)d_in[1];
    const float* dw_w   = (const float*)d_in[2];
    const float* proj_w = (const float*)d_in[3];
    const float* temp   = (const float*)d_in[4];
    const float* attns  = (const float*)d_in[5];
    float* out = (float*)d_out;

    const size_t perbB = (size_t)QKVC * HW * 4;
    auto need = [&](int nb) -> size_t {
        return (size_t)nb * 2 * perbB + 4u * QKVC * CDIM + 4096;
    };
    int NB = 4;
    while (NB > 1 && need(NB) > ws_size) NB >>= 1;

    const long fstride = (long)(perbB / 4);
    const long ustride = (long)(perbB / 2);

    const size_t PART_B  = 27u << 20;
    const size_t PART2_B = (29u << 20) + (512u << 10);
    const size_t ATT_B   = 30u << 20;
    const size_t WM_B    = 31u << 20;
    const size_t MH_B    = 32u << 20;
    const size_t ML_B    = 33u << 20;

    char* buf1 = (char*)d_ws;
    char* buf2 = buf1 + (size_t)NB * perbB;
    u16* Ah = (u16*)(buf2 + (size_t)NB * perbB);
    u16* Al = Ah + (size_t)QKVC * CDIM;

    convA_kernel<<<dim3((QKVC * CDIM + 255) / 256), 256, 0, stream>>>(qkv_w, Ah, Al, QKVC * CDIM);

    for (int b0 = 0; b0 < 4; b0 += NB) {
        const int nb = NB;
        float* pre = (float*)buf1;
        float* dwb = (float*)buf2;
        u16* xt_h = (u16*)buf2;                u16* xt_l = xt_h + (size_t)HW * CDIM;
        u16* vt_h = (u16*)buf1;                u16* vt_l = vt_h + (size_t)HW * CDIM;
        float* part  = (float*)(buf1 + PART_B);
        float* part2 = (float*)(buf1 + PART2_B);
        float* attn  = (float*)(buf1 + ATT_B);
        float* Wm    = (float*)(buf1 + WM_B);
        u16* Mh = (u16*)(buf1 + MH_B);
        u16* Ml = (u16*)(buf1 + ML_B);

        // 1) x -> xt (transposed bf16 hi/lo)
        convT_kernel<<<dim3(HW / 32, CDIM / 32, nb), 256, 0, stream>>>(
            x + (size_t)b0 * CDIM * HW, xt_h, xt_l, (long)CDIM * HW, ustride);
        // 2) pre = qkv_w @ x  (MFMA split-bf16)
        mfma_gemm<<<dim3(HW / 256, QKVC / 128, nb), 512, 98304, stream>>>(
            Ah, Al, xt_h, xt_l, pre, QKVC / 128, 0L, ustride, fstride);
        // 3) depthwise 3x3 (overwrites xt with dwb)
        dwconv_kernel<<<dim3(QKVC * HW / 8 / 256, nb), 256, 0, stream>>>(pre, dw_w, dwb);
        // 4) attn partials + sumsq partials
        attn_partial_kernel<<<dim3(NSPLIT, HEADS, nb), 256, 0, stream>>>(dwb, part, part2,
                                                                         fstride, fstride);
        // 5) reduce + inv-norms + scale (9-way parallel)
        attn_reduce_kernel<<<dim3(9, HEADS, nb), 256, 0, stream>>>(part, part2, temp, attn,
                                                                   fstride, fstride, fstride);
        // 6) two-stage masked softmax -> W (wave-per-row, shuffle-based)
        maskw_kernel<<<dim3(12, HEADS, nb), 256, 0, stream>>>(attn, attns, Wm, fstride, fstride);
        // 7) M = proj @ blockdiag(W) -> bf16 hi/lo
        mbuild_kernel<<<dim3(CDIM * CDIM / 256, nb), 256, 0, stream>>>(proj_w, Wm, Mh, Ml,
                                                                       fstride, ustride);
        // 8) v -> vt (transposed bf16 hi/lo)
        convT_kernel<<<dim3(HW / 32, CDIM / 32, nb), 256, 0, stream>>>(
            dwb + (size_t)2 * CDIM * HW, vt_h, vt_l, fstride, ustride);
        // 9) out = M @ v (MFMA split-bf16)
        mfma_gemm<<<dim3(HW / 256, CDIM / 128, nb), 512, 98304, stream>>>(
            Mh, Ml, vt_h, vt_l, out + (size_t)b0 * CDIM * HW, CDIM / 128,
            ustride, ustride, (long)CDIM * HW);
    }
}

// Round 5
// 696.920 us; speedup vs baseline: 2.5419x; 1.0023x over previous
//
#include <hip/hip_runtime.h>
#include <math.h>

#define HW     16384
#define WIDTH  128
#define CDIM   384
#define QKVC   1152
#define HEADS  8
#define CH     48
#define NSPLIT 32
#define GK     384

typedef unsigned short u16;
typedef short bf16x8 __attribute__((ext_vector_type(8)));
typedef float f32x4 __attribute__((ext_vector_type(4)));

// ---- fp32 -> bf16 hi/lo split (RNE both) ----
__device__ __forceinline__ void split2(float x, u16& h, u16& l) {
    union { float f; unsigned u; } a, b, c;
    a.f = x;
    unsigned hu = (a.u + 0x7fffu + ((a.u >> 16) & 1u)) & 0xffff0000u;
    b.u = hu;
    h = (u16)(hu >> 16);
    c.f = x - b.f;
    l = (u16)((c.u + 0x7fffu + ((c.u >> 16) & 1u)) >> 16);
}

__device__ __forceinline__ void gload16(const void* g, void* l) {
    __builtin_amdgcn_global_load_lds((const __attribute__((address_space(1))) unsigned int*)g,
                                     (__attribute__((address_space(3))) unsigned int*)l, 16, 0, 0);
}

// ---------------- MFMA split-bf16 GEMM, counted-vmcnt pipeline ----------------
// C[M,HW] fp32 = A[M,384] @ B[384,HW]; A row-major bf16 hi/lo planes,
// B TRANSPOSED as Bt[HW,384] bf16 hi/lo planes. BM=128 BN=256 BK=32,
// 512 thr (8 waves 2x4), double-buffered LDS (96KB), 2-deep prefetch,
// vmcnt(6) steady state (never 0 in main loop), raw s_barrier (no drain).
__global__ __launch_bounds__(512)
void mfma_gemm(const u16* __restrict__ Ah, const u16* __restrict__ Al,
               const u16* __restrict__ Bh, const u16* __restrict__ Bl,
               float* __restrict__ C, int nmb,
               long abs_, long bbs, long cbs)
{
    extern __shared__ char smem[];
    const int tot = gridDim.x * gridDim.y;
    const int per = tot >> 3;
    const int fl  = blockIdx.x + gridDim.x * blockIdx.y;
    const int f2  = (fl & 7) * per + (fl >> 3);
    const int nblk = f2 / nmb, mblk = f2 % nmb;
    const int b = blockIdx.z;
    Ah += (long)b * abs_; Al += (long)b * abs_;
    Bh += (long)b * bbs;  Bl += (long)b * bbs;
    C  += (long)b * cbs;
    const int m0 = mblk * 128, n0 = nblk * 256;

    const int tid  = threadIdx.x;
    const int wave = tid >> 6, lane = tid & 63;
    const int lr = lane & 15, lg = lane >> 4;
    const int wm = wave >> 2, wn = wave & 3;
    const int wb = wave * 1024;

    const int sr  = tid >> 2;
    const int kxs = (tid & 3) ^ ((sr >> 1) & 3);

    f32x4 acc[4][4];
#pragma unroll
    for (int i = 0; i < 4; ++i)
#pragma unroll
        for (int j = 0; j < 4; ++j) acc[i][j] = (f32x4){0.f, 0.f, 0.f, 0.f};

#define STAGE(bufsel, kt) do {                                                     \
        char* LL = smem + (bufsel) * 49152;                                        \
        const long ko = (long)(kt) * 32 + kxs * 8;                                 \
        gload16(Ah + (long)(m0 + sr) * GK + ko,        LL + wb);                   \
        gload16(Al + (long)(m0 + sr) * GK + ko,        LL + 8192  + wb);           \
        gload16(Bh + (long)(n0 + sr) * GK + ko,        LL + 16384 + wb);           \
        gload16(Bh + (long)(n0 + 128 + sr) * GK + ko,  LL + 24576 + wb);           \
        gload16(Bl + (long)(n0 + sr) * GK + ko,        LL + 32768 + wb);           \
        gload16(Bl + (long)(n0 + 128 + sr) * GK + ko,  LL + 40960 + wb);           \
    } while (0)

    STAGE(0, 0);                 // 6 loads in flight
    STAGE(1, 1);                 // 12 in flight
    int cur = 0;
    for (int kt = 0; kt < 12; ++kt) {        // GK/32 == 12
        // wait for THIS buffer's 6 loads; keep the next buffer's 6 in flight
        if (kt < 11) asm volatile("s_waitcnt vmcnt(6)" ::: "memory");
        else         asm volatile("s_waitcnt vmcnt(0)" ::: "memory");
        __builtin_amdgcn_s_barrier();        // all waves' loads for cur landed

        const char* L = smem + cur * 49152;
        bf16x8 af[4][2], bf[4][2];
#pragma unroll
        for (int mi = 0; mi < 4; ++mi) {
            int r = wm * 64 + mi * 16 + lr;
            int off = r * 64 + (((lg ^ (r >> 1)) & 3) << 4);
            af[mi][0] = *(const bf16x8*)(L + off);
            af[mi][1] = *(const bf16x8*)(L + 8192 + off);
        }
#pragma unroll
        for (int ni = 0; ni < 4; ++ni) {
            int r = wn * 64 + ni * 16 + lr;
            int off = r * 64 + (((lg ^ (r >> 1)) & 3) << 4);
            bf[ni][0] = *(const bf16x8*)(L + 16384 + off);
            bf[ni][1] = *(const bf16x8*)(L + 32768 + off);
        }
        asm volatile("s_waitcnt lgkmcnt(0)" ::: "memory");
        __builtin_amdgcn_sched_barrier(0);   // keep MFMA below the wait (rule #18)
        __builtin_amdgcn_s_barrier();        // all waves done reading cur
        if (kt < 10) STAGE(cur, kt + 2);     // overwrite cur with tile kt+2

        __builtin_amdgcn_s_setprio(1);
#pragma unroll
        for (int mi = 0; mi < 4; ++mi)
#pragma unroll
            for (int ni = 0; ni < 4; ++ni) {
                acc[mi][ni] = __builtin_amdgcn_mfma_f32_16x16x32_bf16(af[mi][0], bf[ni][0], acc[mi][ni], 0, 0, 0);
                acc[mi][ni] = __builtin_amdgcn_mfma_f32_16x16x32_bf16(af[mi][0], bf[ni][1], acc[mi][ni], 0, 0, 0);
                acc[mi][ni] = __builtin_amdgcn_mfma_f32_16x16x32_bf16(af[mi][1], bf[ni][0], acc[mi][ni], 0, 0, 0);
            }
        __builtin_amdgcn_s_setprio(0);
        cur ^= 1;
    }
#undef STAGE

#pragma unroll
    for (int mi = 0; mi < 4; ++mi)
#pragma unroll
        for (int ni = 0; ni < 4; ++ni) {
            int row = m0 + wm * 64 + mi * 16 + lg * 4;
            int col = n0 + wn * 64 + ni * 16 + lr;
            float* cp = C + (long)row * HW + col;
            cp[0]          = acc[mi][ni][0];
            cp[(long)HW]   = acc[mi][ni][1];
            cp[2L * HW]    = acc[mi][ni][2];
            cp[3L * HW]    = acc[mi][ni][3];
        }
}

// ---------------- transpose + split convert: [384][HW] fp32 -> [HW][384] bf16 hi/lo ----
// packed ushort2 stores (channel pairs) to halve write requests
__global__ __launch_bounds__(256)
void convT_kernel(const float* __restrict__ in, u16* __restrict__ oh, u16* __restrict__ ol,
                  long ibs, long obs)
{
    const int b = blockIdx.z;
    in += (long)b * ibs; oh += (long)b * obs; ol += (long)b * obs;
    __shared__ float t[32][33];
    const int p0 = blockIdx.x * 32, c0 = blockIdx.y * 32;
    const int ty = threadIdx.x >> 5, tx = threadIdx.x & 31;
#pragma unroll
    for (int it = 0; it < 4; ++it) {
        int c = ty + it * 8;
        t[c][tx] = in[(long)(c0 + c) * HW + p0 + tx];
    }
    __syncthreads();
    const int cp = threadIdx.x & 15;        // channel pair index
    const int py = threadIdx.x >> 4;        // pixel 0..15
#pragma unroll
    for (int half = 0; half < 2; ++half) {
        int p = py + half * 16;
        u16 h0, l0, h1, l1;
        split2(t[2 * cp][p], h0, l0);
        split2(t[2 * cp + 1][p], h1, l1);
        long o = (long)(p0 + p) * CDIM + c0 + 2 * cp;
        *(ushort2*)&oh[o] = (ushort2){h0, h1};
        *(ushort2*)&ol[o] = (ushort2){l0, l1};
    }
}

// ---------------- elementwise split convert (qkv_w) ----------------
__global__ __launch_bounds__(256)
void convA_kernel(const float* __restrict__ in, u16* __restrict__ oh, u16* __restrict__ ol, int n)
{
    int i = blockIdx.x * 256 + threadIdx.x;
    if (i < n) split2(in[i], oh[i], ol[i]);
}

// ---------------- depthwise 3x3, pad 1 — 8 px/thread, float4 loads/stores ----------------
__global__ __launch_bounds__(256)
void dwconv_kernel(const float* __restrict__ in, const float* __restrict__ w,
                   float* __restrict__ out)
{
    const long base = (long)blockIdx.y * QKVC * HW;
    const int idx = blockIdx.x * 256 + threadIdx.x;      // over QKVC*HW/8
    const int ch = idx >> 11;
    const int wi = idx & 2047;
    const int y = wi >> 4, x0 = (wi & 15) * 8;
    const float* wp = w + ch * 9;
    const float* ip = in + base + (long)ch * HW;
    float o[8] = {0.f, 0.f, 0.f, 0.f, 0.f, 0.f, 0.f, 0.f};
#pragma unroll
    for (int dy = -1; dy <= 1; ++dy) {
        int yy = y + dy;
        if ((unsigned)yy >= 128u) continue;
        const float* rp = ip + yy * WIDTH + x0;
        float4 a  = *(const float4*)rp;
        float4 bq = *(const float4*)(rp + 4);
        float v[10] = { (x0 > 0) ? rp[-1] : 0.f,
                        a.x, a.y, a.z, a.w, bq.x, bq.y, bq.z, bq.w,
                        (x0 < 120) ? rp[8] : 0.f };
        float w0 = wp[(dy + 1) * 3], w1 = wp[(dy + 1) * 3 + 1], w2 = wp[(dy + 1) * 3 + 2];
#pragma unroll
        for (int j = 0; j < 8; ++j)
            o[j] = fmaf(w0, v[j], fmaf(w1, v[j + 1], fmaf(w2, v[j + 2], o[j])));
    }
    float* op = out + base + (long)ch * HW + y * WIDTH + x0;
    *(float4*)op       = (float4){o[0], o[1], o[2], o[3]};
    *(float4*)(op + 4) = (float4){o[4], o[5], o[6], o[7]};
}

// ---------------- attn partial: 48x48 dots over 512-px slice + q/k sumsq partials ----
__global__ __launch_bounds__(256)
void attn_partial_kernel(const float* __restrict__ dw, float* __restrict__ part,
                         float* __restrict__ part2, long ps, long p2s)
{
    const int split = blockIdx.x, h = blockIdx.y, b = blockIdx.z;
    const int n0 = split * (HW / NSPLIT);
    const float* qbase = dw + ((long)b * QKVC + h * CH) * HW;
    const float* kbase = dw + ((long)b * QKVC + CDIM + h * CH) * HW;
    __shared__ float qs[64][CH];
    __shared__ float ks[64][CH];
    const int tid = threadIdx.x;
    const int tr = tid >> 4, tc = tid & 15;
    const int c0 = tr * 3, d0 = tc * 3;
    float acc[3][3] = {{0.f}};
    float qss[3] = {0.f, 0.f, 0.f}, kss[3] = {0.f, 0.f, 0.f};
    const int cA = tid >> 4;
    const int nq = (tid & 15) * 4;
    for (int ns = 0; ns < HW / NSPLIT; ns += 64) {
        __syncthreads();
#pragma unroll
        for (int t = 0; t < 3; ++t) {
            int c = cA + t * 16;
            float4 qv = *(const float4*)(qbase + (long)c * HW + n0 + ns + nq);
            float4 kv = *(const float4*)(kbase + (long)c * HW + n0 + ns + nq);
            qs[nq + 0][c] = qv.x; qs[nq + 1][c] = qv.y;
            qs[nq + 2][c] = qv.z; qs[nq + 3][c] = qv.w;
            ks[nq + 0][c] = kv.x; ks[nq + 1][c] = kv.y;
            ks[nq + 2][c] = kv.z; ks[nq + 3][c] = kv.w;
            qss[t] += qv.x * qv.x + qv.y * qv.y + qv.z * qv.z + qv.w * qv.w;
            kss[t] += kv.x * kv.x + kv.y * kv.y + kv.z * kv.z + kv.w * kv.w;
        }
        __syncthreads();
#pragma unroll 8
        for (int n = 0; n < 64; ++n) {
            float q0 = qs[n][c0], q1 = qs[n][c0 + 1], q2 = qs[n][c0 + 2];
            float k0 = ks[n][d0], k1 = ks[n][d0 + 1], k2 = ks[n][d0 + 2];
            acc[0][0] = fmaf(q0, k0, acc[0][0]); acc[0][1] = fmaf(q0, k1, acc[0][1]); acc[0][2] = fmaf(q0, k2, acc[0][2]);
            acc[1][0] = fmaf(q1, k0, acc[1][0]); acc[1][1] = fmaf(q1, k1, acc[1][1]); acc[1][2] = fmaf(q1, k2, acc[1][2]);
            acc[2][0] = fmaf(q2, k0, acc[2][0]); acc[2][1] = fmaf(q2, k1, acc[2][1]); acc[2][2] = fmaf(q2, k2, acc[2][2]);
        }
    }
#pragma unroll
    for (int m = 1; m < 16; m <<= 1) {
#pragma unroll
        for (int t = 0; t < 3; ++t) {
            qss[t] += __shfl_xor(qss[t], m);
            kss[t] += __shfl_xor(kss[t], m);
        }
    }
    if ((tid & 15) == 0) {
        float* p2 = part2 + (long)b * p2s + ((long)h * NSPLIT + split) * 96;
#pragma unroll
        for (int t = 0; t < 3; ++t) {
            p2[cA + t * 16]      = qss[t];
            p2[48 + cA + t * 16] = kss[t];
        }
    }
    float* po = part + (long)b * ps + ((long)h * NSPLIT + split) * (CH * CH);
#pragma unroll
    for (int i = 0; i < 3; ++i)
#pragma unroll
        for (int j = 0; j < 3; ++j)
            po[(c0 + i) * CH + d0 + j] = acc[i][j];
}

// ---------------- attn reduce: sum partials, inv-norms from sumsq, temperature ----
// grid (9, HEADS, nb): 9 x 256 = 2304 = 48*48 entries per (b,h)
__global__ __launch_bounds__(256)
void attn_reduce_kernel(const float* __restrict__ part, const float* __restrict__ part2,
                        const float* __restrict__ temp, float* __restrict__ attn,
                        long ps, long p2s, long as_)
{
    const int seg = blockIdx.x, h = blockIdx.y, b = blockIdx.z;
    const float* pp = part + (long)b * ps + (long)h * NSPLIT * (CH * CH);
    const float* p2 = part2 + (long)b * p2s + (long)h * NSPLIT * 96;
    __shared__ float sinv[96];
    if (threadIdx.x < 96) {
        float s = 0.f;
        for (int sp = 0; sp < NSPLIT; ++sp) s += p2[sp * 96 + threadIdx.x];
        sinv[threadIdx.x] = 1.f / fmaxf(sqrtf(s), 1e-12f);
    }
    __syncthreads();
    const float t = temp[h];
    const int idx = seg * 256 + threadIdx.x;
    const int c = idx / CH, d = idx % CH;
    float s = 0.f;
    for (int sp = 0; sp < NSPLIT; ++sp) s += pp[sp * (CH * CH) + idx];
    attn[(long)b * as_ + (long)h * (CH * CH) + idx] = s * sinv[c] * sinv[48 + d] * t;
}

// ---------------- two-stage masked softmax -> combined weights W ----------------
// Wave-per-row, fully in-register via shuffle broadcast. grid (12, HEADS, nb) x 256.
__global__ __launch_bounds__(256)
void maskw_kernel(const float* __restrict__ attn, const float* __restrict__ attns,
                  float* __restrict__ W, long as_, long ws_)
{
    const int h = blockIdx.y, b = blockIdx.z;
    const int wave = threadIdx.x >> 6, lane = threadIdx.x & 63;
    const int r = blockIdx.x * 4 + wave;                 // 0..47
    const float* ap = attn + (long)b * as_ + (long)h * (CH * CH) + (long)r * CH;
    float a = (lane < CH) ? ap[lane] : -3.4e38f;

    int rank = 0;
#pragma unroll
    for (int j = 0; j < CH; ++j) {
        float aj = __shfl(a, j);
        rank += (aj > a) || (aj == a && j < lane);
    }
    const bool keep = (lane < CH) && (rank < 24);
    float m = keep ? a : -3.4e38f;
#pragma unroll
    for (int o = 32; o > 0; o >>= 1) m = fmaxf(m, __shfl_xor(m, o));
    float e = keep ? expf(a - m) : 0.f;
    float s = e;
#pragma unroll
    for (int o = 32; o > 0; o >>= 1) s += __shfl_xor(s, o);
    const float A1 = e / s;

    int rank2 = 0;
#pragma unroll
    for (int j = 0; j < CH; ++j) {
        float aj = __shfl(A1, j);
        rank2 += (aj > A1) || (aj == A1 && j < lane);
    }
    const bool keep2 = (lane < CH) && (rank2 < 36);
    float m2 = keep2 ? A1 : -3.4e38f;
#pragma unroll
    for (int o = 32; o > 0; o >>= 1) m2 = fmaxf(m2, __shfl_xor(m2, o));
    float e2 = keep2 ? expf(A1 - m2) : 0.f;
    float s2 = e2;
#pragma unroll
    for (int o = 32; o > 0; o >>= 1) s2 += __shfl_xor(s2, o);

    if (lane < CH)
        W[(long)b * ws_ + (long)h * (CH * CH) + (long)r * CH + lane] =
            attns[0] * A1 + attns[1] * (e2 / s2);
}

// ---------------- M = P @ blockdiag(W), written as bf16 hi/lo planes ----------------
__global__ __launch_bounds__(256)
void mbuild_kernel(const float* __restrict__ P, const float* __restrict__ W,
                   u16* __restrict__ Mh, u16* __restrict__ Ml, long ws_, long ms)
{
    const int b = blockIdx.y;
    const int idx = blockIdx.x * 256 + threadIdx.x;
    const int o = idx / CDIM, col = idx % CDIM;
    const int h = col / CH, d = col % CH;
    const float* wp = W + (long)b * ws_ + (long)h * (CH * CH) + d;
    const float* pp = P + (long)o * CDIM + h * CH;
    float s = 0.f;
#pragma unroll
    for (int c = 0; c < CH; ++c) s = fmaf(pp[c], wp[c * CH], s);
    u16 hh, ll;
    split2(s, hh, ll);
    Mh[(long)b * ms + idx] = hh;
    Ml[(long)b * ms + idx] = ll;
}

extern "C" void kernel_launch(void* const* d_in, const int* in_sizes, int n_in,
                              void* d_out, int out_size, void* d_ws, size_t ws_size,
                              hipStream_t stream)
{
    const float* x      = (const float*)d_in[0];
    const float* qkv_w  = (const float*)d_in[1];
    const float* dw_w   = (const float*)d_in[2];
    const float* proj_w = (const float*)d_in[3];
    const float* temp   = (const float*)d_in[4];
    const float* attns  = (const float*)d_in[5];
    float* out = (float*)d_out;

    const size_t perbB = (size_t)QKVC * HW * 4;
    auto need = [&](int nb) -> size_t {
        return (size_t)nb * 2 * perbB + 4u * QKVC * CDIM + 4096;
    };
    int NB = 4;
    while (NB > 1 && need(NB) > ws_size) NB >>= 1;

    const long fstride = (long)(perbB / 4);
    const long ustride = (long)(perbB / 2);

    const size_t PART_B  = 27u << 20;
    const size_t PART2_B = (29u << 20) + (512u << 10);
    const size_t ATT_B   = 30u << 20;
    const size_t WM_B    = 31u << 20;
    const size_t MH_B    = 32u << 20;
    const size_t ML_B    = 33u << 20;

    char* buf1 = (char*)d_ws;
    char* buf2 = buf1 + (size_t)NB * perbB;
    u16* Ah = (u16*)(buf2 + (size_t)NB * perbB);
    u16* Al = Ah + (size_t)QKVC * CDIM;

    convA_kernel<<<dim3((QKVC * CDIM + 255) / 256), 256, 0, stream>>>(qkv_w, Ah, Al, QKVC * CDIM);

    for (int b0 = 0; b0 < 4; b0 += NB) {
        const int nb = NB;
        float* pre = (float*)buf1;
        float* dwb = (float*)buf2;
        u16* xt_h = (u16*)buf2;                u16* xt_l = xt_h + (size_t)HW * CDIM;
        u16* vt_h = (u16*)buf1;                u16* vt_l = vt_h + (size_t)HW * CDIM;
        float* part  = (float*)(buf1 + PART_B);
        float* part2 = (float*)(buf1 + PART2_B);
        float* attn  = (float*)(buf1 + ATT_B);
        float* Wm    = (float*)(buf1 + WM_B);
        u16* Mh = (u16*)(buf1 + MH_B);
        u16* Ml = (u16*)(buf1 + ML_B);

        // 1) x -> xt (transposed bf16 hi/lo)
        convT_kernel<<<dim3(HW / 32, CDIM / 32, nb), 256, 0, stream>>>(
            x + (size_t)b0 * CDIM * HW, xt_h, xt_l, (long)CDIM * HW, ustride);
        // 2) pre = qkv_w @ x  (MFMA split-bf16, counted-vmcnt pipeline)
        mfma_gemm<<<dim3(HW / 256, QKVC / 128, nb), 512, 98304, stream>>>(
            Ah, Al, xt_h, xt_l, pre, QKVC / 128, 0L, ustride, fstride);
        // 3) depthwise 3x3 (overwrites xt with dwb)
        dwconv_kernel<<<dim3(QKVC * HW / 8 / 256, nb), 256, 0, stream>>>(pre, dw_w, dwb);
        // 4) attn partials + sumsq partials
        attn_partial_kernel<<<dim3(NSPLIT, HEADS, nb), 256, 0, stream>>>(dwb, part, part2,
                                                                         fstride, fstride);
        // 5) reduce + inv-norms + scale (9-way parallel)
        attn_reduce_kernel<<<dim3(9, HEADS, nb), 256, 0, stream>>>(part, part2, temp, attn,
                                                                   fstride, fstride, fstride);
        // 6) two-stage masked softmax -> W (wave-per-row, shuffle-based)
        maskw_kernel<<<dim3(12, HEADS, nb), 256, 0, stream>>>(attn, attns, Wm, fstride, fstride);
        // 7) M = proj @ blockdiag(W) -> bf16 hi/lo
        mbuild_kernel<<<dim3(CDIM * CDIM / 256, nb), 256, 0, stream>>>(proj_w, Wm, Mh, Ml,
                                                                       fstride, ustride);
        // 8) v -> vt (transposed bf16 hi/lo)
        convT_kernel<<<dim3(HW / 32, CDIM / 32, nb), 256, 0, stream>>>(
            dwb + (size_t)2 * CDIM * HW, vt_h, vt_l, fstride, ustride);
        // 9) out = M @ v (MFMA split-bf16, counted-vmcnt pipeline)
        mfma_gemm<<<dim3(HW / 256, CDIM / 128, nb), 512, 98304, stream>>>(
            Mh, Ml, vt_h, vt_l, out + (size_t)b0 * CDIM * HW, CDIM / 128,
            ustride, ustride, (long)CDIM * HW);
    }
}